// Round 1
// baseline (1280.480 us; speedup 1.0000x reference)
//
#include <hip/hip_runtime.h>
#include <cstddef>

#define NN    10000
#define PP    12
#define EMAIN 160000
#define EREG  40000
#define OUTD  256
#define HIDD  128

// ---- workspace layout (float offsets) ----
enum : int {
  WS_PROBS    = 0,
  WS_DEGM     = 16,
  WS_DEGR     = WS_DEGM + NN,            // 5*NN
  WS_AGGM     = WS_DEGR + 5 * NN,        // NN*48
  WS_TX1      = WS_AGGM + NN * 48,       // 5*NN*48
  WS_ZERO_END = WS_TX1 + 5 * NN * 48,
  WS_DINVM    = WS_ZERO_END,
  WS_DINV2M   = WS_DINVM + NN,
  WS_DINVR    = WS_DINV2M + NN,          // 5*NN
  WS_NORMM    = WS_DINVR + 5 * NN,       // EMAIN
  WS_NORMR    = WS_NORMM + EMAIN,        // 5*EREG
  WS_MCAT     = WS_NORMR + 5 * EREG,     // 24*OUTD
  WS_BIASH    = WS_MCAT + 24 * OUTD,
  WS_AZ       = WS_BIASH + OUTD,
  WS_AR       = WS_AZ + 4 * OUTD,
  WS_AH       = WS_AR + 4 * OUTD,
  WS_BZ       = WS_AH + 4 * OUTD,
  WS_BR       = WS_BZ + OUTD,
  WS_BH       = WS_BR + OUTD,
  WS_TOTAL    = WS_BH + OUTD
};

__device__ __forceinline__ float sigm(float v) { return 1.f / (1.f + __expf(-v)); }
__device__ __forceinline__ float tanh_f(float v) { float e = __expf(2.f * v); return 1.f - 2.f / (e + 1.f); }

__device__ __forceinline__ const int* sel_i(int r, const int* a, const int* b, const int* c, const int* d, const int* e) {
  return r == 0 ? a : r == 1 ? b : r == 2 ? c : r == 3 ? d : e;
}
__device__ __forceinline__ const float* sel_f(int r, const float* a, const float* b, const float* c, const float* d, const float* e) {
  return r == 0 ? a : r == 1 ? b : r == 2 ? c : r == 3 ? d : e;
}

__global__ void probs_kernel(const float* __restrict__ att, float* __restrict__ probs) {
  if (threadIdx.x == 0 && blockIdx.x == 0) {
    float m = att[0];
    for (int i = 1; i < PP; ++i) m = fmaxf(m, att[i]);
    float e[PP]; float s = 0.f;
    for (int i = 0; i < PP; ++i) { e[i] = __expf(att[i] - m); s += e[i]; }
    float inv = 1.f / s;
    for (int i = 0; i < PP; ++i) probs[i] = e[i] * inv;
  }
}

__global__ void deg_kernel(const int* __restrict__ eim,
    const int* e0, const int* e1, const int* e2, const int* e3, const int* e4,
    const float* w0, const float* w1, const float* w2, const float* w3, const float* w4,
    float* __restrict__ degm, float* __restrict__ degr) {
  int g = blockIdx.x * 256 + threadIdx.x;
  if (g >= EMAIN + 5 * EREG) return;
  if (g < EMAIN) {
    atomicAdd(&degm[eim[EMAIN + g]], 1.0f);         // GCN in-degree (by dst)
  } else {
    int q = g - EMAIN;
    int r = q / EREG;
    int e = q - r * EREG;
    const int* ei = sel_i(r, e0, e1, e2, e3, e4);
    const float* w = sel_f(r, w0, w1, w2, w3, w4);
    atomicAdd(&degr[r * NN + ei[e]], w[e]);         // cheb weighted degree (by src)
  }
}

__global__ void dinv_kernel(const float* __restrict__ degm, const float* __restrict__ degr,
    float* __restrict__ dinvm, float* __restrict__ dinv2m, float* __restrict__ dinvr) {
  int g = blockIdx.x * 256 + threadIdx.x;
  if (g >= 6 * NN) return;
  if (g < NN) {
    float c = degm[g] + 1.0f;
    dinvm[g] = rsqrtf(c);
    dinv2m[g] = 1.0f / c;
  } else {
    int q = g - NN;
    float dv = degr[q];
    dinvr[q] = dv > 0.f ? rsqrtf(fmaxf(dv, 1e-12f)) : 0.f;
  }
}

__global__ void norm_kernel(const int* __restrict__ eim,
    const int* e0, const int* e1, const int* e2, const int* e3, const int* e4,
    const float* w0, const float* w1, const float* w2, const float* w3, const float* w4,
    const float* __restrict__ dinvm, const float* __restrict__ dinvr,
    float* __restrict__ normm, float* __restrict__ normr) {
  int g = blockIdx.x * 256 + threadIdx.x;
  if (g >= EMAIN + 5 * EREG) return;
  if (g < EMAIN) {
    int s = eim[g], d = eim[EMAIN + g];
    normm[g] = dinvm[s] * dinvm[d];
  } else {
    int q = g - EMAIN;
    int r = q / EREG;
    int e = q - r * EREG;
    const int* ei = sel_i(r, e0, e1, e2, e3, e4);
    const float* w = sel_f(r, w0, w1, w2, w3, w4);
    int s = ei[e], d = ei[EREG + e];
    normr[q] = -(dinvr[r * NN + s] * w[e] * dinvr[r * NN + d]);  // negated: Tx1 = -segsum
  }
}

// one thread per (edge, f*12+p): scatter all 48 values of an edge
__global__ void scatter_kernel(const float* __restrict__ x,
    const int* __restrict__ eim,
    const int* e0, const int* e1, const int* e2, const int* e3, const int* e4,
    const float* __restrict__ normm, const float* __restrict__ normr,
    float* __restrict__ aggm, float* __restrict__ tx1) {
  int g = blockIdx.x * 256 + threadIdx.x;   // grid sized exactly (EMAIN+5*EREG)*48
  int eg = g / 48;
  int i = g - eg * 48;
  int s, d; float nv; float* out;
  if (eg < EMAIN) {
    s = eim[eg]; d = eim[EMAIN + eg]; nv = normm[eg]; out = aggm;
  } else {
    int q = eg - EMAIN;
    int r = q / EREG;
    int e = q - r * EREG;
    const int* ei = sel_i(r, e0, e1, e2, e3, e4);
    s = ei[e]; d = ei[EREG + e];
    nv = normr[q];
    out = tx1 + (size_t)r * (NN * 48);
  }
  atomicAdd(&out[d * 48 + i], nv * x[s * 48 + i]);
}

// fold small matrices: Mcat (24x256), bias_h, Az/Ar/Ah (4x256), bz/br/bh
__global__ __launch_bounds__(256) void prep_kernel(
    const float* __restrict__ W0, const float* __restrict__ W1, const float* __restrict__ chebb,
    const float* __restrict__ lcW, const float* __restrict__ lcb,
    const float* __restrict__ gzW, const float* __restrict__ gzb,
    const float* __restrict__ grW, const float* __restrict__ grb,
    const float* __restrict__ ghW, const float* __restrict__ ghb,
    const float* __restrict__ lzW, const float* __restrict__ lzb,
    const float* __restrict__ lrW, const float* __restrict__ lrb,
    const float* __restrict__ lhW, const float* __restrict__ lhb,
    float* __restrict__ Mcat, float* __restrict__ biash,
    float* __restrict__ Az, float* __restrict__ Ar, float* __restrict__ Ah,
    float* __restrict__ bz, float* __restrict__ br, float* __restrict__ bh) {
  const int j = threadIdx.x;
  float m0[4] = {0, 0, 0, 0};
  float m1[5][4] = {};
  float bhh = lcb[j];
  for (int k = 0; k < OUTD; ++k) {
    float s5 = 0.f;
#pragma unroll
    for (int r = 0; r < 5; ++r) {
      float w = lcW[(r * OUTD + k) * OUTD + j];
      s5 += w;
#pragma unroll
      for (int f = 0; f < 4; ++f) m1[r][f] += W1[f * OUTD + k] * w;
    }
#pragma unroll
    for (int f = 0; f < 4; ++f) m0[f] += W0[f * OUTD + k] * s5;
    bhh += chebb[k] * s5;
  }
#pragma unroll
  for (int f = 0; f < 4; ++f) Mcat[f * OUTD + j] = m0[f];
#pragma unroll
  for (int r = 0; r < 5; ++r)
#pragma unroll
    for (int f = 0; f < 4; ++f) Mcat[(4 + 4 * r + f) * OUTD + j] = m1[r][f];
  biash[j] = bhh;

  float az[4] = {0, 0, 0, 0}, ar[4] = {0, 0, 0, 0}, ah[4] = {0, 0, 0, 0};
  float vbz = lzb[j], vbr = lrb[j], vbh = lhb[j];
  for (int k = 0; k < OUTD; ++k) {
    float wz = lzW[k * OUTD + j];
    float wr = lrW[k * OUTD + j];
    float wh = lhW[k * OUTD + j];
#pragma unroll
    for (int f = 0; f < 4; ++f) {
      az[f] += gzW[f * OUTD + k] * wz;
      ar[f] += grW[f * OUTD + k] * wr;
      ah[f] += ghW[f * OUTD + k] * wh;
    }
    vbz += gzb[k] * wz; vbr += grb[k] * wr; vbh += ghb[k] * wh;
  }
#pragma unroll
  for (int f = 0; f < 4; ++f) { Az[f * OUTD + j] = az[f]; Ar[f * OUTD + j] = ar[f]; Ah[f * OUTD + j] = ah[f]; }
  bz[j] = vbz; br[j] = vbr; bh[j] = vbh;
}

// fused per-node GRU over all 12 periods. block = 1 node, 64 threads, 4 cols/thread
__global__ __launch_bounds__(64) void gru_kernel(
    const float* __restrict__ x,
    const float* __restrict__ lzW,
    const float* __restrict__ lrW,
    const float* __restrict__ lhW,
    const float* __restrict__ ws,
    float* __restrict__ Hout) {
  const int n = blockIdx.x;
  const int t = threadIdx.x;
  const int j0 = t * 4;
  __shared__ __align__(16) float U[PP][28];
  __shared__ __align__(16) float Hs[PP][OUTD];

  const float* aggm   = ws + WS_AGGM;
  const float* tx1    = ws + WS_TX1;
  const float* dinv2m = ws + WS_DINV2M;
  const float* Mcat   = ws + WS_MCAT;
  const float* biash  = ws + WS_BIASH;
  const float* Az = ws + WS_AZ;
  const float* Ar = ws + WS_AR;
  const float* Ah = ws + WS_AH;
  const float* bz = ws + WS_BZ;
  const float* br = ws + WS_BR;
  const float* bh = ws + WS_BH;
  const float* probs = ws + WS_PROBS;

  {
    const float d2 = dinv2m[n];
    for (int idx = t; idx < PP * 28; idx += 64) {
      int p = idx / 28;
      int i = idx - p * 28;
      float v;
      if (i < 4) {
        v = x[n * 48 + i * 12 + p];
      } else if (i < 24) {
        int q = i - 4; int r = q >> 2; int f = q & 3;
        v = tx1[(size_t)(r * NN + n) * 48 + f * 12 + p];
      } else {
        int f = i - 24;
        v = aggm[n * 48 + f * 12 + p] + d2 * x[n * 48 + f * 12 + p];
      }
      U[p][i] = v;
    }
  }
  __syncthreads();

  // h = leaky_relu(U[0..23] @ Mcat + bias_h)
  float h_[PP][4];
#pragma unroll
  for (int p = 0; p < PP; ++p) {
    float4 a = *(const float4*)(biash + j0);
#pragma unroll
    for (int i = 0; i < 24; ++i) {
      float u = U[p][i];
      float4 m = *(const float4*)(Mcat + i * OUTD + j0);
      a.x += u * m.x; a.y += u * m.y; a.z += u * m.z; a.w += u * m.w;
    }
    a.x = a.x > 0.f ? a.x : 0.01f * a.x;
    a.y = a.y > 0.f ? a.y : 0.01f * a.y;
    a.z = a.z > 0.f ? a.z : 0.01f * a.z;
    a.w = a.w > 0.f ? a.w : 0.01f * a.w;
    h_[p][0] = a.x; h_[p][1] = a.y; h_[p][2] = a.z; h_[p][3] = a.w;
    *(float4*)(&Hs[p][j0]) = a;
  }
  __syncthreads();

  // Z and R pre-activations
  float4 accz[PP], accr[PP];
  {
    const float4 vbz = *(const float4*)(bz + j0);
    const float4 vbr = *(const float4*)(br + j0);
    float4 az_[4], ar_[4];
#pragma unroll
    for (int f = 0; f < 4; ++f) {
      az_[f] = *(const float4*)(Az + f * OUTD + j0);
      ar_[f] = *(const float4*)(Ar + f * OUTD + j0);
    }
#pragma unroll
    for (int p = 0; p < PP; ++p) {
      float u0 = U[p][24], u1 = U[p][25], u2 = U[p][26], u3 = U[p][27];
      accz[p].x = vbz.x + u0 * az_[0].x + u1 * az_[1].x + u2 * az_[2].x + u3 * az_[3].x;
      accz[p].y = vbz.y + u0 * az_[0].y + u1 * az_[1].y + u2 * az_[2].y + u3 * az_[3].y;
      accz[p].z = vbz.z + u0 * az_[0].z + u1 * az_[1].z + u2 * az_[2].z + u3 * az_[3].z;
      accz[p].w = vbz.w + u0 * az_[0].w + u1 * az_[1].w + u2 * az_[2].w + u3 * az_[3].w;
      accr[p].x = vbr.x + u0 * ar_[0].x + u1 * ar_[1].x + u2 * ar_[2].x + u3 * ar_[3].x;
      accr[p].y = vbr.y + u0 * ar_[0].y + u1 * ar_[1].y + u2 * ar_[2].y + u3 * ar_[3].y;
      accr[p].z = vbr.z + u0 * ar_[0].z + u1 * ar_[1].z + u2 * ar_[2].z + u3 * ar_[3].z;
      accr[p].w = vbr.w + u0 * ar_[0].w + u1 * ar_[1].w + u2 * ar_[2].w + u3 * ar_[3].w;
    }
  }
  for (int k = 0; k < OUTD; k += 2) {
    const float4 wz0 = *(const float4*)(lzW + (OUTD + k) * OUTD + j0);
    const float4 wz1 = *(const float4*)(lzW + (OUTD + k + 1) * OUTD + j0);
    const float4 wr0 = *(const float4*)(lrW + (OUTD + k) * OUTD + j0);
    const float4 wr1 = *(const float4*)(lrW + (OUTD + k + 1) * OUTD + j0);
#pragma unroll
    for (int p = 0; p < PP; ++p) {
      const float2 hv = *(const float2*)(&Hs[p][k]);
      accz[p].x += hv.x * wz0.x + hv.y * wz1.x;
      accz[p].y += hv.x * wz0.y + hv.y * wz1.y;
      accz[p].z += hv.x * wz0.z + hv.y * wz1.z;
      accz[p].w += hv.x * wz0.w + hv.y * wz1.w;
      accr[p].x += hv.x * wr0.x + hv.y * wr1.x;
      accr[p].y += hv.x * wr0.y + hv.y * wr1.y;
      accr[p].z += hv.x * wr0.z + hv.y * wr1.z;
      accr[p].w += hv.x * wr0.w + hv.y * wr1.w;
    }
  }
#pragma unroll
  for (int p = 0; p < PP; ++p) {
    accz[p].x = sigm(accz[p].x); accz[p].y = sigm(accz[p].y);
    accz[p].z = sigm(accz[p].z); accz[p].w = sigm(accz[p].w);
    accr[p].x = sigm(accr[p].x); accr[p].y = sigm(accr[p].y);
    accr[p].z = sigm(accr[p].z); accr[p].w = sigm(accr[p].w);
  }
  __syncthreads();   // all reads of Hs (h) done
#pragma unroll
  for (int p = 0; p < PP; ++p) {   // overwrite Hs with h*R
    float4 hr;
    hr.x = h_[p][0] * accr[p].x;
    hr.y = h_[p][1] * accr[p].y;
    hr.z = h_[p][2] * accr[p].z;
    hr.w = h_[p][3] * accr[p].w;
    *(float4*)(&Hs[p][j0]) = hr;
  }
  __syncthreads();

  float4 acch[PP];
  {
    const float4 vbh = *(const float4*)(bh + j0);
    float4 ah_[4];
#pragma unroll
    for (int f = 0; f < 4; ++f) ah_[f] = *(const float4*)(Ah + f * OUTD + j0);
#pragma unroll
    for (int p = 0; p < PP; ++p) {
      float u0 = U[p][24], u1 = U[p][25], u2 = U[p][26], u3 = U[p][27];
      acch[p].x = vbh.x + u0 * ah_[0].x + u1 * ah_[1].x + u2 * ah_[2].x + u3 * ah_[3].x;
      acch[p].y = vbh.y + u0 * ah_[0].y + u1 * ah_[1].y + u2 * ah_[2].y + u3 * ah_[3].y;
      acch[p].z = vbh.z + u0 * ah_[0].z + u1 * ah_[1].z + u2 * ah_[2].z + u3 * ah_[3].z;
      acch[p].w = vbh.w + u0 * ah_[0].w + u1 * ah_[1].w + u2 * ah_[2].w + u3 * ah_[3].w;
    }
  }
  for (int k = 0; k < OUTD; k += 2) {
    const float4 wh0 = *(const float4*)(lhW + (OUTD + k) * OUTD + j0);
    const float4 wh1 = *(const float4*)(lhW + (OUTD + k + 1) * OUTD + j0);
#pragma unroll
    for (int p = 0; p < PP; ++p) {
      const float2 hv = *(const float2*)(&Hs[p][k]);
      acch[p].x += hv.x * wh0.x + hv.y * wh1.x;
      acch[p].y += hv.x * wh0.y + hv.y * wh1.y;
      acch[p].z += hv.x * wh0.z + hv.y * wh1.z;
      acch[p].w += hv.x * wh0.w + hv.y * wh1.w;
    }
  }
  float4 ho; ho.x = 0.f; ho.y = 0.f; ho.z = 0.f; ho.w = 0.f;
#pragma unroll
  for (int p = 0; p < PP; ++p) {
    const float pr = probs[p];
    float htx = tanh_f(acch[p].x);
    float hty = tanh_f(acch[p].y);
    float htz = tanh_f(acch[p].z);
    float htw = tanh_f(acch[p].w);
    ho.x += pr * (accz[p].x * h_[p][0] + (1.f - accz[p].x) * htx);
    ho.y += pr * (accz[p].y * h_[p][1] + (1.f - accz[p].y) * hty);
    ho.z += pr * (accz[p].z * h_[p][2] + (1.f - accz[p].z) * htz);
    ho.w += pr * (accz[p].w * h_[p][3] + (1.f - accz[p].w) * htw);
  }
  *(float4*)(Hout + n * OUTD + j0) = ho;
}

// o = relu(relu(H) @ out1_W + b1) @ out2_W + b2 ; 8 nodes per block
__global__ __launch_bounds__(128) void head_kernel(
    const float* __restrict__ H,
    const float* __restrict__ W1, const float* __restrict__ b1,
    const float* __restrict__ W2, const float* __restrict__ b2,
    float* __restrict__ o) {
  const int n0 = blockIdx.x * 8;
  const int t = threadIdx.x;
  __shared__ float hr[8][OUTD];
  __shared__ float hid[8][130];
  for (int idx = t; idx < 8 * OUTD; idx += 128) {
    int r = idx >> 8, c = idx & 255;
    float v = H[(n0 + r) * OUTD + c];
    hr[r][c] = v > 0.f ? v : 0.f;
  }
  __syncthreads();
  float acc[8];
  float bb = b1[t];
#pragma unroll
  for (int r = 0; r < 8; ++r) acc[r] = bb;
  for (int k = 0; k < OUTD; ++k) {
    float w = W1[k * HIDD + t];
#pragma unroll
    for (int r = 0; r < 8; ++r) acc[r] += hr[r][k] * w;
  }
#pragma unroll
  for (int r = 0; r < 8; ++r) hid[r][t] = acc[r] > 0.f ? acc[r] : 0.f;
  __syncthreads();
  if (t < 96) {
    int r = t / 12, dd = t - r * 12;
    float a = b2[dd];
    for (int k = 0; k < HIDD; ++k) a += hid[r][k] * W2[k * 12 + dd];
    o[(n0 + r) * 12 + dd] = a;
  }
}

extern "C" void kernel_launch(void* const* d_in, const int* in_sizes, int n_in,
                              void* d_out, int out_size, void* d_ws, size_t ws_size,
                              hipStream_t stream) {
  (void)in_sizes; (void)n_in; (void)out_size; (void)ws_size;
  const float* x    = (const float*)d_in[0];
  const int*   eim  = (const int*)d_in[1];
  const int*   ei0  = (const int*)d_in[2];
  const float* ew0  = (const float*)d_in[3];
  const int*   ei1  = (const int*)d_in[4];
  const float* ew1  = (const float*)d_in[5];
  const int*   ei2  = (const int*)d_in[6];
  const float* ew2  = (const float*)d_in[7];
  const int*   ei3  = (const int*)d_in[8];
  const float* ew3  = (const float*)d_in[9];
  const int*   ei4  = (const int*)d_in[10];
  const float* ew4  = (const float*)d_in[11];
  const float* chebW0 = (const float*)d_in[12];
  const float* chebW1 = (const float*)d_in[13];
  const float* chebb  = (const float*)d_in[14];
  const float* lcW  = (const float*)d_in[15];
  const float* lcb  = (const float*)d_in[16];
  const float* att  = (const float*)d_in[17];
  const float* gzW  = (const float*)d_in[18];
  const float* gzb  = (const float*)d_in[19];
  const float* grW  = (const float*)d_in[20];
  const float* grb  = (const float*)d_in[21];
  const float* ghW  = (const float*)d_in[22];
  const float* ghb  = (const float*)d_in[23];
  const float* lzW  = (const float*)d_in[24];
  const float* lzb  = (const float*)d_in[25];
  const float* lrW  = (const float*)d_in[26];
  const float* lrb  = (const float*)d_in[27];
  const float* lhW  = (const float*)d_in[28];
  const float* lhb  = (const float*)d_in[29];
  const float* o1W  = (const float*)d_in[30];
  const float* o1b  = (const float*)d_in[31];
  const float* o2W  = (const float*)d_in[32];
  const float* o2b  = (const float*)d_in[33];

  float* ws = (float*)d_ws;
  float* out = (float*)d_out;
  float* o_out = out;                 // (N,12) flat
  float* H_out = out + NN * 12;       // (N,256) flat

  hipMemsetAsync(ws, 0, (size_t)WS_ZERO_END * sizeof(float), stream);
  probs_kernel<<<1, 64, 0, stream>>>(att, ws + WS_PROBS);
  deg_kernel<<<(EMAIN + 5 * EREG + 255) / 256, 256, 0, stream>>>(
      eim, ei0, ei1, ei2, ei3, ei4, ew0, ew1, ew2, ew3, ew4,
      ws + WS_DEGM, ws + WS_DEGR);
  dinv_kernel<<<(6 * NN + 255) / 256, 256, 0, stream>>>(
      ws + WS_DEGM, ws + WS_DEGR, ws + WS_DINVM, ws + WS_DINV2M, ws + WS_DINVR);
  norm_kernel<<<(EMAIN + 5 * EREG + 255) / 256, 256, 0, stream>>>(
      eim, ei0, ei1, ei2, ei3, ei4, ew0, ew1, ew2, ew3, ew4,
      ws + WS_DINVM, ws + WS_DINVR, ws + WS_NORMM, ws + WS_NORMR);
  scatter_kernel<<<((EMAIN + 5 * EREG) * 48) / 256, 256, 0, stream>>>(
      x, eim, ei0, ei1, ei2, ei3, ei4,
      ws + WS_NORMM, ws + WS_NORMR, ws + WS_AGGM, ws + WS_TX1);
  prep_kernel<<<1, 256, 0, stream>>>(
      chebW0, chebW1, chebb, lcW, lcb,
      gzW, gzb, grW, grb, ghW, ghb,
      lzW, lzb, lrW, lrb, lhW, lhb,
      ws + WS_MCAT, ws + WS_BIASH, ws + WS_AZ, ws + WS_AR, ws + WS_AH,
      ws + WS_BZ, ws + WS_BR, ws + WS_BH);
  gru_kernel<<<NN, 64, 0, stream>>>(x, lzW, lrW, lhW, ws, H_out);
  head_kernel<<<NN / 8, 128, 0, stream>>>(H_out, o1W, o1b, o2W, o2b, o_out);
}

// Round 4
// 639.986 us; speedup vs baseline: 2.0008x; 2.0008x over previous
//
#include <hip/hip_runtime.h>
#include <cstddef>

#define NN    10000
#define PP    12
#define EMAIN 160000
#define EREG  40000
#define OUTD  256
#define HIDD  128

typedef __attribute__((ext_vector_type(8))) short bf16x8;
typedef __attribute__((ext_vector_type(4))) float f32x4;

// ---- workspace layout (float offsets) ----
enum : int {
  WS_PROBS    = 0,
  WS_DEGM     = 16,
  WS_DEGR     = WS_DEGM + NN,            // 5*NN
  WS_AGGM     = WS_DEGR + 5 * NN,        // NN*48
  WS_TX1      = WS_AGGM + NN * 48,       // 5*NN*48
  WS_ZERO_END = WS_TX1 + 5 * NN * 48,
  WS_DINVM    = WS_ZERO_END,
  WS_DINV2M   = WS_DINVM + NN,
  WS_DINVR    = WS_DINV2M + NN,          // 5*NN
  WS_NORMM    = WS_DINVR + 5 * NN,       // EMAIN
  WS_NORMR    = WS_NORMM + EMAIN,        // 5*EREG
  WS_MCAT     = WS_NORMR + 5 * EREG,     // 24*OUTD (fp32)
  WS_BIASH    = WS_MCAT + 24 * OUTD,
  WS_AZ       = WS_BIASH + OUTD,         // 4*OUTD
  WS_AR       = WS_AZ + 4 * OUTD,
  WS_AH       = WS_AR + 4 * OUTD,
  WS_BZ       = WS_AH + 4 * OUTD,
  WS_BR       = WS_BZ + OUTD,
  WS_BH       = WS_BR + OUTD,
  WS_MCT      = WS_BH + OUTD,            // 256*32 bf16 = 4096 floats
  WS_WZT      = WS_MCT + 4096,           // 256*288 bf16 = 36864 floats each
  WS_WRT      = WS_WZT + 36864,
  WS_WHT      = WS_WRT + 36864,
  WS_TOTAL    = WS_WHT + 36864
};

__device__ __forceinline__ float sigm(float v) { return 1.f / (1.f + __expf(-v)); }
__device__ __forceinline__ float tanh_f(float v) { float e = __expf(2.f * v); return 1.f - 2.f / (e + 1.f); }

// float -> bf16 bits, round-nearest-even
__device__ __forceinline__ short bf16b(float v) {
  unsigned x = __float_as_uint(v);
  unsigned r = (x + 0x7fffu + ((x >> 16) & 1u)) >> 16;
  return (short)r;
}
__device__ __forceinline__ float upk_lo(unsigned u) { return __uint_as_float(u << 16); }
__device__ __forceinline__ float upk_hi(unsigned u) { return __uint_as_float(u & 0xffff0000u); }
__device__ __forceinline__ unsigned pk2(float a, float b) {
  return (unsigned)(unsigned short)bf16b(a) | ((unsigned)(unsigned short)bf16b(b) << 16);
}

__device__ __forceinline__ const int* sel_i(int r, const int* a, const int* b, const int* c, const int* d, const int* e) {
  return r == 0 ? a : r == 1 ? b : r == 2 ? c : r == 3 ? d : e;
}
__device__ __forceinline__ const float* sel_f(int r, const float* a, const float* b, const float* c, const float* d, const float* e) {
  return r == 0 ? a : r == 1 ? b : r == 2 ? c : r == 3 ? d : e;
}

__global__ void probs_kernel(const float* __restrict__ att, float* __restrict__ probs) {
  if (threadIdx.x == 0 && blockIdx.x == 0) {
    float m = att[0];
    for (int i = 1; i < PP; ++i) m = fmaxf(m, att[i]);
    float e[PP]; float s = 0.f;
    for (int i = 0; i < PP; ++i) { e[i] = __expf(att[i] - m); s += e[i]; }
    float inv = 1.f / s;
    for (int i = 0; i < PP; ++i) probs[i] = e[i] * inv;
  }
}

__global__ void deg_kernel(const int* __restrict__ eim,
    const int* e0, const int* e1, const int* e2, const int* e3, const int* e4,
    const float* w0, const float* w1, const float* w2, const float* w3, const float* w4,
    float* __restrict__ degm, float* __restrict__ degr) {
  int g = blockIdx.x * 256 + threadIdx.x;
  if (g >= EMAIN + 5 * EREG) return;
  if (g < EMAIN) {
    atomicAdd(&degm[eim[EMAIN + g]], 1.0f);
  } else {
    int q = g - EMAIN;
    int r = q / EREG;
    int e = q - r * EREG;
    const int* ei = sel_i(r, e0, e1, e2, e3, e4);
    const float* w = sel_f(r, w0, w1, w2, w3, w4);
    atomicAdd(&degr[r * NN + ei[e]], w[e]);
  }
}

__global__ void dinv_kernel(const float* __restrict__ degm, const float* __restrict__ degr,
    float* __restrict__ dinvm, float* __restrict__ dinv2m, float* __restrict__ dinvr) {
  int g = blockIdx.x * 256 + threadIdx.x;
  if (g >= 6 * NN) return;
  if (g < NN) {
    float c = degm[g] + 1.0f;
    dinvm[g] = rsqrtf(c);
    dinv2m[g] = 1.0f / c;
  } else {
    int q = g - NN;
    float dv = degr[q];
    dinvr[q] = dv > 0.f ? rsqrtf(fmaxf(dv, 1e-12f)) : 0.f;
  }
}

__global__ void norm_kernel(const int* __restrict__ eim,
    const int* e0, const int* e1, const int* e2, const int* e3, const int* e4,
    const float* w0, const float* w1, const float* w2, const float* w3, const float* w4,
    const float* __restrict__ dinvm, const float* __restrict__ dinvr,
    float* __restrict__ normm, float* __restrict__ normr) {
  int g = blockIdx.x * 256 + threadIdx.x;
  if (g >= EMAIN + 5 * EREG) return;
  if (g < EMAIN) {
    int s = eim[g], d = eim[EMAIN + g];
    normm[g] = dinvm[s] * dinvm[d];
  } else {
    int q = g - EMAIN;
    int r = q / EREG;
    int e = q - r * EREG;
    const int* ei = sel_i(r, e0, e1, e2, e3, e4);
    const float* w = sel_f(r, w0, w1, w2, w3, w4);
    int s = ei[e], d = ei[EREG + e];
    normr[q] = -(dinvr[r * NN + s] * w[e] * dinvr[r * NN + d]);
  }
}

__global__ void scatter_kernel(const float* __restrict__ x,
    const int* __restrict__ eim,
    const int* e0, const int* e1, const int* e2, const int* e3, const int* e4,
    const float* __restrict__ normm, const float* __restrict__ normr,
    float* __restrict__ aggm, float* __restrict__ tx1) {
  int g = blockIdx.x * 256 + threadIdx.x;
  int eg = g / 48;
  int i = g - eg * 48;
  int s, d; float nv; float* out;
  if (eg < EMAIN) {
    s = eim[eg]; d = eim[EMAIN + eg]; nv = normm[eg]; out = aggm;
  } else {
    int q = eg - EMAIN;
    int r = q / EREG;
    int e = q - r * EREG;
    const int* ei = sel_i(r, e0, e1, e2, e3, e4);
    s = ei[e]; d = ei[EREG + e];
    nv = normr[q];
    out = tx1 + (size_t)r * (NN * 48);
  }
  atomicAdd(&out[d * 48 + i], nv * x[s * 48 + i]);
}

// fold small matrices (fp32): Mcat (24x256), bias_h, Az/Ar/Ah (4x256), bz/br/bh
__global__ __launch_bounds__(256) void prep_kernel(
    const float* __restrict__ W0, const float* __restrict__ W1, const float* __restrict__ chebb,
    const float* __restrict__ lcW, const float* __restrict__ lcb,
    const float* __restrict__ gzW, const float* __restrict__ gzb,
    const float* __restrict__ grW, const float* __restrict__ grb,
    const float* __restrict__ ghW, const float* __restrict__ ghb,
    const float* __restrict__ lzW, const float* __restrict__ lzb,
    const float* __restrict__ lrW, const float* __restrict__ lrb,
    const float* __restrict__ lhW, const float* __restrict__ lhb,
    float* __restrict__ Mcat, float* __restrict__ biash,
    float* __restrict__ Az, float* __restrict__ Ar, float* __restrict__ Ah,
    float* __restrict__ bz, float* __restrict__ br, float* __restrict__ bh) {
  const int j = threadIdx.x;
  float m0[4] = {0, 0, 0, 0};
  float m1[5][4] = {};
  float bhh = lcb[j];
  for (int k = 0; k < OUTD; ++k) {
    float s5 = 0.f;
#pragma unroll
    for (int r = 0; r < 5; ++r) {
      float w = lcW[(r * OUTD + k) * OUTD + j];
      s5 += w;
#pragma unroll
      for (int f = 0; f < 4; ++f) m1[r][f] += W1[f * OUTD + k] * w;
    }
#pragma unroll
    for (int f = 0; f < 4; ++f) m0[f] += W0[f * OUTD + k] * s5;
    bhh += chebb[k] * s5;
  }
#pragma unroll
  for (int f = 0; f < 4; ++f) Mcat[f * OUTD + j] = m0[f];
#pragma unroll
  for (int r = 0; r < 5; ++r)
#pragma unroll
    for (int f = 0; f < 4; ++f) Mcat[(4 + 4 * r + f) * OUTD + j] = m1[r][f];
  biash[j] = bhh;

  float az[4] = {0, 0, 0, 0}, ar[4] = {0, 0, 0, 0}, ah[4] = {0, 0, 0, 0};
  float vbz = lzb[j], vbr = lrb[j], vbh = lhb[j];
  for (int k = 0; k < OUTD; ++k) {
    float wz = lzW[k * OUTD + j];
    float wr = lrW[k * OUTD + j];
    float wh = lhW[k * OUTD + j];
#pragma unroll
    for (int f = 0; f < 4; ++f) {
      az[f] += gzW[f * OUTD + k] * wz;
      ar[f] += grW[f * OUTD + k] * wr;
      ah[f] += ghW[f * OUTD + k] * wh;
    }
    vbz += gzb[k] * wz; vbr += grb[k] * wr; vbh += ghb[k] * wh;
  }
#pragma unroll
  for (int f = 0; f < 4; ++f) { Az[f * OUTD + j] = az[f]; Ar[f * OUTD + j] = ar[f]; Ah[f * OUTD + j] = ah[f]; }
  bz[j] = vbz; br[j] = vbr; bh[j] = vbh;
}

// build transposed bf16 weight panels: WT[col j][k 0..287]
//   k<256        -> bottom half of l?W (row 256+k, col j)
//   k in 280..283 -> A?fold[f=k-280][j]   (aggx contribution)
//   else          -> 0
// and McT[col j][k 0..31] (k<24 -> Mcat[k][j])
__global__ void prepT_kernel(
    const float* __restrict__ lzW, const float* __restrict__ lrW, const float* __restrict__ lhW,
    float* __restrict__ ws) {
  int bx = blockIdx.x;
  int g = bx >> 8;
  int j = bx & 255;
  if (g < 3) {
    const float* Wsrc = g == 0 ? lzW : g == 1 ? lrW : lhW;
    const float* Afold = ws + WS_AZ + g * (4 * OUTD);
    short* dst = (short*)(ws + (g == 0 ? WS_WZT : g == 1 ? WS_WRT : WS_WHT));
    for (int k = threadIdx.x; k < 288; k += 128) {
      float v = 0.f;
      if (k < 256) v = Wsrc[(256 + k) * OUTD + j];
      else if (k >= 280 && k < 284) v = Afold[(k - 280) * OUTD + j];
      dst[j * 288 + k] = bf16b(v);
    }
  } else {
    const float* Mcat = ws + WS_MCAT;
    short* mct = (short*)(ws + WS_MCT);
    for (int k = threadIdx.x; k < 32; k += 128) {
      float v = (k < 24) ? Mcat[k * OUTD + j] : 0.f;
      mct[j * 32 + k] = bf16b(v);
    }
  }
}

#define GATE_MFMA(WT) do {                                                          \
  _Pragma("unroll") for (int m_ = 0; m_ < 6; ++m_)                                  \
    _Pragma("unroll") for (int nt_ = 0; nt_ < 4; ++nt_)                             \
      acc[m_][nt_] = (f32x4){0.f, 0.f, 0.f, 0.f};                                   \
  _Pragma("unroll") for (int ks_ = 0; ks_ < 9; ++ks_) {                             \
    bf16x8 bfr_[4];                                                                 \
    _Pragma("unroll") for (int nt_ = 0; nt_ < 4; ++nt_)                             \
      bfr_[nt_] = *(const bf16x8*)((WT) + (size_t)(wcol + nt_ * 16 + lr) * 288 + ks_ * 32 + 8 * lg); \
    _Pragma("unroll") for (int m_ = 0; m_ < 6; ++m_) {                              \
      bf16x8 af_ = *(const bf16x8*)(&As[m_ * 16 + lr][ks_ * 32 + 8 * lg]);          \
      _Pragma("unroll") for (int nt_ = 0; nt_ < 4; ++nt_)                           \
        acc[m_][nt_] = __builtin_amdgcn_mfma_f32_16x16x32_bf16(af_, bfr_[nt_], acc[m_][nt_], 0, 0, 0); \
    }                                                                               \
  }                                                                                 \
} while (0)

// fused MFMA GRU: 8 nodes x 12 periods = 96 rows per block; 4 waves x 64 cols
__global__ __launch_bounds__(256, 2) void gru_mfma_kernel(
    const float* __restrict__ x,
    const float* __restrict__ ws,
    float* __restrict__ Hout) {
  const int n0 = blockIdx.x * 8;
  const int t = threadIdx.x;
  const int w = t >> 6;
  const int l = t & 63;
  const int lr = l & 15;
  const int lg = l >> 4;
  const int wcol = w * 64;

  __shared__ __align__(16) short As[96][296];   // rows: p*8+nl ; k: 0..255 h/hR, 256..287 U/aggx

  const float* aggm   = ws + WS_AGGM;
  const float* tx1    = ws + WS_TX1;
  const float* dinv2m = ws + WS_DINV2M;
  const float* biash  = ws + WS_BIASH;
  const float* bz     = ws + WS_BZ;
  const float* br     = ws + WS_BR;
  const float* bh     = ws + WS_BH;
  const float* probs  = ws + WS_PROBS;
  const short* McT = (const short*)(ws + WS_MCT);
  const short* WzT = (const short*)(ws + WS_WZT);
  const short* WrT = (const short*)(ws + WS_WRT);
  const short* WhT = (const short*)(ws + WS_WHT);

  // ---- stage U (bf16) into As[row][256..287]
  for (int idx = t; idx < 96 * 32; idx += 256) {
    int row = idx >> 5, s = idx & 31;
    int p = row >> 3, nl = row & 7, n = n0 + nl;
    float v = 0.f;
    if (s < 4) {
      v = x[n * 48 + s * 12 + p];
    } else if (s < 24) {
      int q = s - 4; int r = q >> 2; int f = q & 3;
      v = tx1[(size_t)(r * NN + n) * 48 + f * 12 + p];
    } else if (s < 28) {
      int f = s - 24;
      v = aggm[n * 48 + f * 12 + p] + dinv2m[n] * x[n * 48 + f * 12 + p];
    }
    As[row][256 + s] = bf16b(v);
  }
  __syncthreads();

  f32x4 acc[6][4];

  // ---- h = leaky_relu(U @ Mcat + biash)
  {
    bf16x8 bm[4];
#pragma unroll
    for (int nt = 0; nt < 4; ++nt)
      bm[nt] = *(const bf16x8*)(McT + (size_t)(wcol + nt * 16 + lr) * 32 + 8 * lg);
    const f32x4 zf = {0.f, 0.f, 0.f, 0.f};
#pragma unroll
    for (int m = 0; m < 6; ++m) {
      bf16x8 af = *(const bf16x8*)(&As[m * 16 + lr][256 + 8 * lg]);
#pragma unroll
      for (int nt = 0; nt < 4; ++nt)
        acc[m][nt] = __builtin_amdgcn_mfma_f32_16x16x32_bf16(af, bm[nt], zf, 0, 0, 0);
    }
  }
  unsigned hp[6][4][2];
#pragma unroll
  for (int nt = 0; nt < 4; ++nt) {
    int col = wcol + nt * 16 + lr;
    float bb = biash[col];
#pragma unroll
    for (int m = 0; m < 6; ++m) {
      f32x4 a = acc[m][nt];
      int rmb = m * 16 + 4 * lg;
      float v0 = a[0] + bb; v0 = v0 > 0.f ? v0 : 0.01f * v0;
      float v1 = a[1] + bb; v1 = v1 > 0.f ? v1 : 0.01f * v1;
      float v2 = a[2] + bb; v2 = v2 > 0.f ? v2 : 0.01f * v2;
      float v3 = a[3] + bb; v3 = v3 > 0.f ? v3 : 0.01f * v3;
      short s0 = bf16b(v0), s1 = bf16b(v1), s2 = bf16b(v2), s3 = bf16b(v3);
      As[rmb + 0][col] = s0; As[rmb + 1][col] = s1;
      As[rmb + 2][col] = s2; As[rmb + 3][col] = s3;
      hp[m][nt][0] = (unsigned)(unsigned short)s0 | ((unsigned)(unsigned short)s1 << 16);
      hp[m][nt][1] = (unsigned)(unsigned short)s2 | ((unsigned)(unsigned short)s3 << 16);
    }
  }
  __syncthreads();

  // ---- Z
  GATE_MFMA(WzT);
  unsigned zp[6][4][2];
#pragma unroll
  for (int nt = 0; nt < 4; ++nt) {
    float bb = bz[wcol + nt * 16 + lr];
#pragma unroll
    for (int m = 0; m < 6; ++m) {
      f32x4 a = acc[m][nt];
      zp[m][nt][0] = pk2(sigm(a[0] + bb), sigm(a[1] + bb));
      zp[m][nt][1] = pk2(sigm(a[2] + bb), sigm(a[3] + bb));
    }
  }

  // ---- R ; overwrite As k<256 with h*R
  GATE_MFMA(WrT);
  __syncthreads();
#pragma unroll
  for (int nt = 0; nt < 4; ++nt) {
    int col = wcol + nt * 16 + lr;
    float bb = br[col];
#pragma unroll
    for (int m = 0; m < 6; ++m) {
      f32x4 a = acc[m][nt];
      int rmb = m * 16 + 4 * lg;
      As[rmb + 0][col] = bf16b(upk_lo(hp[m][nt][0]) * sigm(a[0] + bb));
      As[rmb + 1][col] = bf16b(upk_hi(hp[m][nt][0]) * sigm(a[1] + bb));
      As[rmb + 2][col] = bf16b(upk_lo(hp[m][nt][1]) * sigm(a[2] + bb));
      As[rmb + 3][col] = bf16b(upk_hi(hp[m][nt][1]) * sigm(a[3] + bb));
    }
  }
  __syncthreads();

  // ---- Ht ; final combine + attention-weighted p-reduction
  GATE_MFMA(WhT);
  float pr[6];
#pragma unroll
  for (int m = 0; m < 6; ++m) pr[m] = probs[2 * m + (lg >> 1)];
  float wsum[4][4];
#pragma unroll
  for (int nt = 0; nt < 4; ++nt)
#pragma unroll
    for (int q = 0; q < 4; ++q) wsum[nt][q] = 0.f;
#pragma unroll
  for (int nt = 0; nt < 4; ++nt) {
    int col = wcol + nt * 16 + lr;
    float bb = bh[col];
#pragma unroll
    for (int m = 0; m < 6; ++m) {
      f32x4 a = acc[m][nt];
      float hv0 = upk_lo(hp[m][nt][0]), hv1 = upk_hi(hp[m][nt][0]);
      float hv2 = upk_lo(hp[m][nt][1]), hv3 = upk_hi(hp[m][nt][1]);
      float zv0 = upk_lo(zp[m][nt][0]), zv1 = upk_hi(zp[m][nt][0]);
      float zv2 = upk_lo(zp[m][nt][1]), zv3 = upk_hi(zp[m][nt][1]);
      float t0 = tanh_f(a[0] + bb);
      float t1 = tanh_f(a[1] + bb);
      float t2 = tanh_f(a[2] + bb);
      float t3 = tanh_f(a[3] + bb);
      wsum[nt][0] += pr[m] * (zv0 * hv0 + (1.f - zv0) * t0);
      wsum[nt][1] += pr[m] * (zv1 * hv1 + (1.f - zv1) * t1);
      wsum[nt][2] += pr[m] * (zv2 * hv2 + (1.f - zv2) * t2);
      wsum[nt][3] += pr[m] * (zv3 * hv3 + (1.f - zv3) * t3);
    }
  }
#pragma unroll
  for (int nt = 0; nt < 4; ++nt)
#pragma unroll
    for (int q = 0; q < 4; ++q) {
      float tot = wsum[nt][q] + __shfl_xor(wsum[nt][q], 32);
      if (lg < 2)
        Hout[(size_t)(n0 + 4 * lg + q) * OUTD + wcol + nt * 16 + lr] = tot;
    }
}

// o = relu(relu(H) @ out1_W + b1) @ out2_W + b2 ; 8 nodes per block
__global__ __launch_bounds__(128) void head_kernel(
    const float* __restrict__ H,
    const float* __restrict__ W1, const float* __restrict__ b1,
    const float* __restrict__ W2, const float* __restrict__ b2,
    float* __restrict__ o) {
  const int n0 = blockIdx.x * 8;
  const int t = threadIdx.x;
  __shared__ float hr[8][OUTD];
  __shared__ float hid[8][130];
  for (int idx = t; idx < 8 * OUTD; idx += 128) {
    int r = idx >> 8, c = idx & 255;
    float v = H[(n0 + r) * OUTD + c];
    hr[r][c] = v > 0.f ? v : 0.f;
  }
  __syncthreads();
  float acc[8];
  float bb = b1[t];
#pragma unroll
  for (int r = 0; r < 8; ++r) acc[r] = bb;
  for (int k = 0; k < OUTD; ++k) {
    float w = W1[k * HIDD + t];
#pragma unroll
    for (int r = 0; r < 8; ++r) acc[r] += hr[r][k] * w;
  }
#pragma unroll
  for (int r = 0; r < 8; ++r) hid[r][t] = acc[r] > 0.f ? acc[r] : 0.f;
  __syncthreads();
  if (t < 96) {
    int r = t / 12, dd = t - r * 12;
    float a = b2[dd];
    for (int k = 0; k < HIDD; ++k) a += hid[r][k] * W2[k * 12 + dd];
    o[(n0 + r) * 12 + dd] = a;
  }
}

extern "C" void kernel_launch(void* const* d_in, const int* in_sizes, int n_in,
                              void* d_out, int out_size, void* d_ws, size_t ws_size,
                              hipStream_t stream) {
  (void)in_sizes; (void)n_in; (void)out_size; (void)ws_size;
  const float* x    = (const float*)d_in[0];
  const int*   eim  = (const int*)d_in[1];
  const int*   ei0  = (const int*)d_in[2];
  const float* ew0  = (const float*)d_in[3];
  const int*   ei1  = (const int*)d_in[4];
  const float* ew1  = (const float*)d_in[5];
  const int*   ei2  = (const int*)d_in[6];
  const float* ew2  = (const float*)d_in[7];
  const int*   ei3  = (const int*)d_in[8];
  const float* ew3  = (const float*)d_in[9];
  const int*   ei4  = (const int*)d_in[10];
  const float* ew4  = (const float*)d_in[11];
  const float* chebW0 = (const float*)d_in[12];
  const float* chebW1 = (const float*)d_in[13];
  const float* chebb  = (const float*)d_in[14];
  const float* lcW  = (const float*)d_in[15];
  const float* lcb  = (const float*)d_in[16];
  const float* att  = (const float*)d_in[17];
  const float* gzW  = (const float*)d_in[18];
  const float* gzb  = (const float*)d_in[19];
  const float* grW  = (const float*)d_in[20];
  const float* grb  = (const float*)d_in[21];
  const float* ghW  = (const float*)d_in[22];
  const float* ghb  = (const float*)d_in[23];
  const float* lzW  = (const float*)d_in[24];
  const float* lzb  = (const float*)d_in[25];
  const float* lrW  = (const float*)d_in[26];
  const float* lrb  = (const float*)d_in[27];
  const float* lhW  = (const float*)d_in[28];
  const float* lhb  = (const float*)d_in[29];
  const float* o1W  = (const float*)d_in[30];
  const float* o1b  = (const float*)d_in[31];
  const float* o2W  = (const float*)d_in[32];
  const float* o2b  = (const float*)d_in[33];

  float* ws = (float*)d_ws;
  float* out = (float*)d_out;
  float* o_out = out;                 // (N,12) flat
  float* H_out = out + NN * 12;       // (N,256) flat

  hipMemsetAsync(ws, 0, (size_t)WS_ZERO_END * sizeof(float), stream);
  probs_kernel<<<1, 64, 0, stream>>>(att, ws + WS_PROBS);
  deg_kernel<<<(EMAIN + 5 * EREG + 255) / 256, 256, 0, stream>>>(
      eim, ei0, ei1, ei2, ei3, ei4, ew0, ew1, ew2, ew3, ew4,
      ws + WS_DEGM, ws + WS_DEGR);
  dinv_kernel<<<(6 * NN + 255) / 256, 256, 0, stream>>>(
      ws + WS_DEGM, ws + WS_DEGR, ws + WS_DINVM, ws + WS_DINV2M, ws + WS_DINVR);
  norm_kernel<<<(EMAIN + 5 * EREG + 255) / 256, 256, 0, stream>>>(
      eim, ei0, ei1, ei2, ei3, ei4, ew0, ew1, ew2, ew3, ew4,
      ws + WS_DINVM, ws + WS_DINVR, ws + WS_NORMM, ws + WS_NORMR);
  scatter_kernel<<<((EMAIN + 5 * EREG) * 48) / 256, 256, 0, stream>>>(
      x, eim, ei0, ei1, ei2, ei3, ei4,
      ws + WS_NORMM, ws + WS_NORMR, ws + WS_AGGM, ws + WS_TX1);
  prep_kernel<<<1, 256, 0, stream>>>(
      chebW0, chebW1, chebb, lcW, lcb,
      gzW, gzb, grW, grb, ghW, ghb,
      lzW, lzb, lrW, lrb, lhW, lhb,
      ws + WS_MCAT, ws + WS_BIASH, ws + WS_AZ, ws + WS_AR, ws + WS_AH,
      ws + WS_BZ, ws + WS_BR, ws + WS_BH);
  prepT_kernel<<<1024, 128, 0, stream>>>(lzW, lrW, lhW, ws);
  gru_mfma_kernel<<<NN / 8, 256, 0, stream>>>(x, ws, H_out);
  head_kernel<<<NN / 8, 128, 0, stream>>>(H_out, o1W, o1b, o2W, o2b, o_out);
}

// Round 5
// 468.100 us; speedup vs baseline: 2.7355x; 1.3672x over previous
//
#include <hip/hip_runtime.h>
#include <cstddef>

#define NN    10000
#define PP    12
#define EMAIN 160000
#define EREG  40000
#define OUTD  256
#define HIDD  128

typedef __attribute__((ext_vector_type(8))) short bf16x8;
typedef __attribute__((ext_vector_type(4))) float f32x4;

// ---- workspace layout (float offsets) ----
enum : int {
  WS_PROBS    = 0,
  WS_DEGM     = 16,
  WS_DEGR     = WS_DEGM + NN,            // 5*NN
  WS_AGGM     = WS_DEGR + 5 * NN,        // NN*48
  WS_TX1      = WS_AGGM + NN * 48,       // 5*NN*48
  WS_ZERO_END = WS_TX1 + 5 * NN * 48,
  WS_DINVM    = WS_ZERO_END,
  WS_DINV2M   = WS_DINVM + NN,
  WS_DINVR    = WS_DINV2M + NN,          // 5*NN
  WS_NORMM    = WS_DINVR + 5 * NN,       // EMAIN
  WS_NORMR    = WS_NORMM + EMAIN,        // 5*EREG
  WS_MCAT     = WS_NORMR + 5 * EREG,     // 24*OUTD (fp32)
  WS_BIASH    = WS_MCAT + 24 * OUTD,
  WS_AZ       = WS_BIASH + OUTD,         // 4*OUTD
  WS_AR       = WS_AZ + 4 * OUTD,
  WS_AH       = WS_AR + 4 * OUTD,
  WS_BZ       = WS_AH + 4 * OUTD,
  WS_BR       = WS_BZ + OUTD,
  WS_BH       = WS_BR + OUTD,
  WS_MCT      = WS_BH + OUTD,            // 256*32 bf16 = 4096 floats
  WS_WZT      = WS_MCT + 4096,           // 256*288 bf16 = 36864 floats each
  WS_WRT      = WS_WZT + 36864,
  WS_WHT      = WS_WRT + 36864,
  WS_TOTAL    = WS_WHT + 36864
};

__device__ __forceinline__ float sigm(float v) { return 1.f / (1.f + __expf(-v)); }
__device__ __forceinline__ float tanh_f(float v) { float e = __expf(2.f * v); return 1.f - 2.f / (e + 1.f); }

// float -> bf16 bits, round-nearest-even
__device__ __forceinline__ short bf16b(float v) {
  unsigned x = __float_as_uint(v);
  unsigned r = (x + 0x7fffu + ((x >> 16) & 1u)) >> 16;
  return (short)r;
}
__device__ __forceinline__ float upk_lo(unsigned u) { return __uint_as_float(u << 16); }
__device__ __forceinline__ float upk_hi(unsigned u) { return __uint_as_float(u & 0xffff0000u); }
__device__ __forceinline__ unsigned pk2(float a, float b) {
  return (unsigned)(unsigned short)bf16b(a) | ((unsigned)(unsigned short)bf16b(b) << 16);
}

__device__ __forceinline__ const int* sel_i(int r, const int* a, const int* b, const int* c, const int* d, const int* e) {
  return r == 0 ? a : r == 1 ? b : r == 2 ? c : r == 3 ? d : e;
}
__device__ __forceinline__ const float* sel_f(int r, const float* a, const float* b, const float* c, const float* d, const float* e) {
  return r == 0 ? a : r == 1 ? b : r == 2 ? c : r == 3 ? d : e;
}

__global__ void probs_kernel(const float* __restrict__ att, float* __restrict__ probs) {
  if (threadIdx.x == 0 && blockIdx.x == 0) {
    float m = att[0];
    for (int i = 1; i < PP; ++i) m = fmaxf(m, att[i]);
    float e[PP]; float s = 0.f;
    for (int i = 0; i < PP; ++i) { e[i] = __expf(att[i] - m); s += e[i]; }
    float inv = 1.f / s;
    for (int i = 0; i < PP; ++i) probs[i] = e[i] * inv;
  }
}

__global__ void deg_kernel(const int* __restrict__ eim,
    const int* e0, const int* e1, const int* e2, const int* e3, const int* e4,
    const float* w0, const float* w1, const float* w2, const float* w3, const float* w4,
    float* __restrict__ degm, float* __restrict__ degr) {
  int g = blockIdx.x * 256 + threadIdx.x;
  if (g >= EMAIN + 5 * EREG) return;
  if (g < EMAIN) {
    atomicAdd(&degm[eim[EMAIN + g]], 1.0f);
  } else {
    int q = g - EMAIN;
    int r = q / EREG;
    int e = q - r * EREG;
    const int* ei = sel_i(r, e0, e1, e2, e3, e4);
    const float* w = sel_f(r, w0, w1, w2, w3, w4);
    atomicAdd(&degr[r * NN + ei[e]], w[e]);
  }
}

__global__ void dinv_kernel(const float* __restrict__ degm, const float* __restrict__ degr,
    float* __restrict__ dinvm, float* __restrict__ dinv2m, float* __restrict__ dinvr) {
  int g = blockIdx.x * 256 + threadIdx.x;
  if (g >= 6 * NN) return;
  if (g < NN) {
    float c = degm[g] + 1.0f;
    dinvm[g] = rsqrtf(c);
    dinv2m[g] = 1.0f / c;
  } else {
    int q = g - NN;
    float dv = degr[q];
    dinvr[q] = dv > 0.f ? rsqrtf(fmaxf(dv, 1e-12f)) : 0.f;
  }
}

__global__ void norm_kernel(const int* __restrict__ eim,
    const int* e0, const int* e1, const int* e2, const int* e3, const int* e4,
    const float* w0, const float* w1, const float* w2, const float* w3, const float* w4,
    const float* __restrict__ dinvm, const float* __restrict__ dinvr,
    float* __restrict__ normm, float* __restrict__ normr) {
  int g = blockIdx.x * 256 + threadIdx.x;
  if (g >= EMAIN + 5 * EREG) return;
  if (g < EMAIN) {
    int s = eim[g], d = eim[EMAIN + g];
    normm[g] = dinvm[s] * dinvm[d];
  } else {
    int q = g - EMAIN;
    int r = q / EREG;
    int e = q - r * EREG;
    const int* ei = sel_i(r, e0, e1, e2, e3, e4);
    const float* w = sel_f(r, w0, w1, w2, w3, w4);
    int s = ei[e], d = ei[EREG + e];
    normr[q] = -(dinvr[r * NN + s] * w[e] * dinvr[r * NN + d]);
  }
}

__global__ void scatter_kernel(const float* __restrict__ x,
    const int* __restrict__ eim,
    const int* e0, const int* e1, const int* e2, const int* e3, const int* e4,
    const float* __restrict__ normm, const float* __restrict__ normr,
    float* __restrict__ aggm, float* __restrict__ tx1) {
  int g = blockIdx.x * 256 + threadIdx.x;
  int eg = g / 48;
  int i = g - eg * 48;
  int s, d; float nv; float* out;
  if (eg < EMAIN) {
    s = eim[eg]; d = eim[EMAIN + eg]; nv = normm[eg]; out = aggm;
  } else {
    int q = eg - EMAIN;
    int r = q / EREG;
    int e = q - r * EREG;
    const int* ei = sel_i(r, e0, e1, e2, e3, e4);
    s = ei[e]; d = ei[EREG + e];
    nv = normr[q];
    out = tx1 + (size_t)r * (NN * 48);
  }
  atomicAdd(&out[d * 48 + i], nv * x[s * 48 + i]);
}

// fold small matrices (fp32): Mcat (24x256), bias_h, Az/Ar/Ah (4x256), bz/br/bh
__global__ __launch_bounds__(256) void prep_kernel(
    const float* __restrict__ W0, const float* __restrict__ W1, const float* __restrict__ chebb,
    const float* __restrict__ lcW, const float* __restrict__ lcb,
    const float* __restrict__ gzW, const float* __restrict__ gzb,
    const float* __restrict__ grW, const float* __restrict__ grb,
    const float* __restrict__ ghW, const float* __restrict__ ghb,
    const float* __restrict__ lzW, const float* __restrict__ lzb,
    const float* __restrict__ lrW, const float* __restrict__ lrb,
    const float* __restrict__ lhW, const float* __restrict__ lhb,
    float* __restrict__ Mcat, float* __restrict__ biash,
    float* __restrict__ Az, float* __restrict__ Ar, float* __restrict__ Ah,
    float* __restrict__ bz, float* __restrict__ br, float* __restrict__ bh) {
  const int j = threadIdx.x;
  float m0[4] = {0, 0, 0, 0};
  float m1[5][4] = {};
  float bhh = lcb[j];
  for (int k = 0; k < OUTD; ++k) {
    float s5 = 0.f;
#pragma unroll
    for (int r = 0; r < 5; ++r) {
      float w = lcW[(r * OUTD + k) * OUTD + j];
      s5 += w;
#pragma unroll
      for (int f = 0; f < 4; ++f) m1[r][f] += W1[f * OUTD + k] * w;
    }
#pragma unroll
    for (int f = 0; f < 4; ++f) m0[f] += W0[f * OUTD + k] * s5;
    bhh += chebb[k] * s5;
  }
#pragma unroll
  for (int f = 0; f < 4; ++f) Mcat[f * OUTD + j] = m0[f];
#pragma unroll
  for (int r = 0; r < 5; ++r)
#pragma unroll
    for (int f = 0; f < 4; ++f) Mcat[(4 + 4 * r + f) * OUTD + j] = m1[r][f];
  biash[j] = bhh;

  float az[4] = {0, 0, 0, 0}, ar[4] = {0, 0, 0, 0}, ah[4] = {0, 0, 0, 0};
  float vbz = lzb[j], vbr = lrb[j], vbh = lhb[j];
  for (int k = 0; k < OUTD; ++k) {
    float wz = lzW[k * OUTD + j];
    float wr = lrW[k * OUTD + j];
    float wh = lhW[k * OUTD + j];
#pragma unroll
    for (int f = 0; f < 4; ++f) {
      az[f] += gzW[f * OUTD + k] * wz;
      ar[f] += grW[f * OUTD + k] * wr;
      ah[f] += ghW[f * OUTD + k] * wh;
    }
    vbz += gzb[k] * wz; vbr += grb[k] * wr; vbh += ghb[k] * wh;
  }
#pragma unroll
  for (int f = 0; f < 4; ++f) { Az[f * OUTD + j] = az[f]; Ar[f * OUTD + j] = ar[f]; Ah[f * OUTD + j] = ah[f]; }
  bz[j] = vbz; br[j] = vbr; bh[j] = vbh;
}

// build transposed bf16 weight panels: WT[col j][k 0..287]
//   k<256        -> bottom half of l?W (row 256+k, col j)
//   k in 280..283 -> A?fold[f=k-280][j]   (aggx contribution)
//   else          -> 0
// and McT[col j][k 0..31] (k<24 -> Mcat[k][j])
__global__ void prepT_kernel(
    const float* __restrict__ lzW, const float* __restrict__ lrW, const float* __restrict__ lhW,
    float* __restrict__ ws) {
  int bx = blockIdx.x;
  int g = bx >> 8;
  int j = bx & 255;
  if (g < 3) {
    const float* Wsrc = g == 0 ? lzW : g == 1 ? lrW : lhW;
    const float* Afold = ws + WS_AZ + g * (4 * OUTD);
    short* dst = (short*)(ws + (g == 0 ? WS_WZT : g == 1 ? WS_WRT : WS_WHT));
    for (int k = threadIdx.x; k < 288; k += 128) {
      float v = 0.f;
      if (k < 256) v = Wsrc[(256 + k) * OUTD + j];
      else if (k >= 280 && k < 284) v = Afold[(k - 280) * OUTD + j];
      dst[j * 288 + k] = bf16b(v);
    }
  } else {
    const float* Mcat = ws + WS_MCAT;
    short* mct = (short*)(ws + WS_MCT);
    for (int k = threadIdx.x; k < 32; k += 128) {
      float v = (k < 24) ? Mcat[k * OUTD + j] : 0.f;
      mct[j * 32 + k] = bf16b(v);
    }
  }
}

#define GATE_MFMA(WT) do {                                                          \
  _Pragma("unroll") for (int m_ = 0; m_ < 6; ++m_)                                  \
    _Pragma("unroll") for (int nt_ = 0; nt_ < 2; ++nt_)                             \
      acc[m_][nt_] = (f32x4){0.f, 0.f, 0.f, 0.f};                                   \
  _Pragma("unroll") for (int ks_ = 0; ks_ < 9; ++ks_) {                             \
    bf16x8 bfr_[2];                                                                 \
    _Pragma("unroll") for (int nt_ = 0; nt_ < 2; ++nt_)                             \
      bfr_[nt_] = *(const bf16x8*)((WT) + (size_t)(wcol + nt_ * 16 + lr) * 288 + ks_ * 32 + 8 * lg); \
    _Pragma("unroll") for (int m_ = 0; m_ < 6; ++m_) {                              \
      bf16x8 af_ = *(const bf16x8*)(&As[m_ * 16 + lr][ks_ * 32 + 8 * lg]);          \
      _Pragma("unroll") for (int nt_ = 0; nt_ < 2; ++nt_)                           \
        acc[m_][nt_] = __builtin_amdgcn_mfma_f32_16x16x32_bf16(af_, bfr_[nt_], acc[m_][nt_], 0, 0, 0); \
    }                                                                               \
  }                                                                                 \
} while (0)

// fused MFMA GRU: 8 nodes x 12 periods = 96 rows per block; 8 waves x 32 cols
// (8 waves x 32 cols instead of 4 x 64: halves per-thread acc/hp/zp state so the
//  ~224-reg live set of the 4-wave version -> ~140, eliminating scratch spills
//  that caused 545 MB/dispatch of HBM traffic in round 4.)
__global__ __launch_bounds__(512, 2) void gru_mfma_kernel(
    const float* __restrict__ x,
    const float* __restrict__ ws,
    float* __restrict__ Hout) {
  const int n0 = blockIdx.x * 8;
  const int t = threadIdx.x;
  const int w = t >> 6;
  const int l = t & 63;
  const int lr = l & 15;
  const int lg = l >> 4;
  const int wcol = w * 32;

  __shared__ __align__(16) short As[96][296];   // rows: p*8+nl ; k: 0..255 h/hR, 256..287 U/aggx

  const float* aggm   = ws + WS_AGGM;
  const float* tx1    = ws + WS_TX1;
  const float* dinv2m = ws + WS_DINV2M;
  const float* biash  = ws + WS_BIASH;
  const float* bz     = ws + WS_BZ;
  const float* br     = ws + WS_BR;
  const float* bh     = ws + WS_BH;
  const float* probs  = ws + WS_PROBS;
  const short* McT = (const short*)(ws + WS_MCT);
  const short* WzT = (const short*)(ws + WS_WZT);
  const short* WrT = (const short*)(ws + WS_WRT);
  const short* WhT = (const short*)(ws + WS_WHT);

  // ---- stage U (bf16) into As[row][256..287]
  for (int idx = t; idx < 96 * 32; idx += 512) {
    int row = idx >> 5, s = idx & 31;
    int p = row >> 3, nl = row & 7, n = n0 + nl;
    float v = 0.f;
    if (s < 4) {
      v = x[n * 48 + s * 12 + p];
    } else if (s < 24) {
      int q = s - 4; int r = q >> 2; int f = q & 3;
      v = tx1[(size_t)(r * NN + n) * 48 + f * 12 + p];
    } else if (s < 28) {
      int f = s - 24;
      v = aggm[n * 48 + f * 12 + p] + dinv2m[n] * x[n * 48 + f * 12 + p];
    }
    As[row][256 + s] = bf16b(v);
  }
  __syncthreads();

  f32x4 acc[6][2];

  // ---- h = leaky_relu(U @ Mcat + biash)
  {
    bf16x8 bm[2];
#pragma unroll
    for (int nt = 0; nt < 2; ++nt)
      bm[nt] = *(const bf16x8*)(McT + (size_t)(wcol + nt * 16 + lr) * 32 + 8 * lg);
    const f32x4 zf = {0.f, 0.f, 0.f, 0.f};
#pragma unroll
    for (int m = 0; m < 6; ++m) {
      bf16x8 af = *(const bf16x8*)(&As[m * 16 + lr][256 + 8 * lg]);
#pragma unroll
      for (int nt = 0; nt < 2; ++nt)
        acc[m][nt] = __builtin_amdgcn_mfma_f32_16x16x32_bf16(af, bm[nt], zf, 0, 0, 0);
    }
  }
  unsigned hp[6][2][2];
#pragma unroll
  for (int nt = 0; nt < 2; ++nt) {
    int col = wcol + nt * 16 + lr;
    float bb = biash[col];
#pragma unroll
    for (int m = 0; m < 6; ++m) {
      f32x4 a = acc[m][nt];
      int rmb = m * 16 + 4 * lg;
      float v0 = a[0] + bb; v0 = v0 > 0.f ? v0 : 0.01f * v0;
      float v1 = a[1] + bb; v1 = v1 > 0.f ? v1 : 0.01f * v1;
      float v2 = a[2] + bb; v2 = v2 > 0.f ? v2 : 0.01f * v2;
      float v3 = a[3] + bb; v3 = v3 > 0.f ? v3 : 0.01f * v3;
      short s0 = bf16b(v0), s1 = bf16b(v1), s2 = bf16b(v2), s3 = bf16b(v3);
      As[rmb + 0][col] = s0; As[rmb + 1][col] = s1;
      As[rmb + 2][col] = s2; As[rmb + 3][col] = s3;
      hp[m][nt][0] = (unsigned)(unsigned short)s0 | ((unsigned)(unsigned short)s1 << 16);
      hp[m][nt][1] = (unsigned)(unsigned short)s2 | ((unsigned)(unsigned short)s3 << 16);
    }
  }
  __syncthreads();

  // ---- Z
  GATE_MFMA(WzT);
  unsigned zp[6][2][2];
#pragma unroll
  for (int nt = 0; nt < 2; ++nt) {
    float bb = bz[wcol + nt * 16 + lr];
#pragma unroll
    for (int m = 0; m < 6; ++m) {
      f32x4 a = acc[m][nt];
      zp[m][nt][0] = pk2(sigm(a[0] + bb), sigm(a[1] + bb));
      zp[m][nt][1] = pk2(sigm(a[2] + bb), sigm(a[3] + bb));
    }
  }

  // ---- R ; overwrite As k<256 with h*R
  GATE_MFMA(WrT);
  __syncthreads();
#pragma unroll
  for (int nt = 0; nt < 2; ++nt) {
    int col = wcol + nt * 16 + lr;
    float bb = br[col];
#pragma unroll
    for (int m = 0; m < 6; ++m) {
      f32x4 a = acc[m][nt];
      int rmb = m * 16 + 4 * lg;
      As[rmb + 0][col] = bf16b(upk_lo(hp[m][nt][0]) * sigm(a[0] + bb));
      As[rmb + 1][col] = bf16b(upk_hi(hp[m][nt][0]) * sigm(a[1] + bb));
      As[rmb + 2][col] = bf16b(upk_lo(hp[m][nt][1]) * sigm(a[2] + bb));
      As[rmb + 3][col] = bf16b(upk_hi(hp[m][nt][1]) * sigm(a[3] + bb));
    }
  }
  __syncthreads();

  // ---- Ht ; final combine + attention-weighted p-reduction
  GATE_MFMA(WhT);
  float pr[6];
#pragma unroll
  for (int m = 0; m < 6; ++m) pr[m] = probs[2 * m + (lg >> 1)];
  float wsum[2][4];
#pragma unroll
  for (int nt = 0; nt < 2; ++nt)
#pragma unroll
    for (int q = 0; q < 4; ++q) wsum[nt][q] = 0.f;
#pragma unroll
  for (int nt = 0; nt < 2; ++nt) {
    int col = wcol + nt * 16 + lr;
    float bb = bh[col];
#pragma unroll
    for (int m = 0; m < 6; ++m) {
      f32x4 a = acc[m][nt];
      float hv0 = upk_lo(hp[m][nt][0]), hv1 = upk_hi(hp[m][nt][0]);
      float hv2 = upk_lo(hp[m][nt][1]), hv3 = upk_hi(hp[m][nt][1]);
      float zv0 = upk_lo(zp[m][nt][0]), zv1 = upk_hi(zp[m][nt][0]);
      float zv2 = upk_lo(zp[m][nt][1]), zv3 = upk_hi(zp[m][nt][1]);
      float t0 = tanh_f(a[0] + bb);
      float t1 = tanh_f(a[1] + bb);
      float t2 = tanh_f(a[2] + bb);
      float t3 = tanh_f(a[3] + bb);
      wsum[nt][0] += pr[m] * (zv0 * hv0 + (1.f - zv0) * t0);
      wsum[nt][1] += pr[m] * (zv1 * hv1 + (1.f - zv1) * t1);
      wsum[nt][2] += pr[m] * (zv2 * hv2 + (1.f - zv2) * t2);
      wsum[nt][3] += pr[m] * (zv3 * hv3 + (1.f - zv3) * t3);
    }
  }
#pragma unroll
  for (int nt = 0; nt < 2; ++nt)
#pragma unroll
    for (int q = 0; q < 4; ++q) {
      float tot = wsum[nt][q] + __shfl_xor(wsum[nt][q], 32);
      if (lg < 2)
        Hout[(size_t)(n0 + 4 * lg + q) * OUTD + wcol + nt * 16 + lr] = tot;
    }
}

// o = relu(relu(H) @ out1_W + b1) @ out2_W + b2 ; 8 nodes per block
__global__ __launch_bounds__(128) void head_kernel(
    const float* __restrict__ H,
    const float* __restrict__ W1, const float* __restrict__ b1,
    const float* __restrict__ W2, const float* __restrict__ b2,
    float* __restrict__ o) {
  const int n0 = blockIdx.x * 8;
  const int t = threadIdx.x;
  __shared__ float hr[8][OUTD];
  __shared__ float hid[8][130];
  for (int idx = t; idx < 8 * OUTD; idx += 128) {
    int r = idx >> 8, c = idx & 255;
    float v = H[(n0 + r) * OUTD + c];
    hr[r][c] = v > 0.f ? v : 0.f;
  }
  __syncthreads();
  float acc[8];
  float bb = b1[t];
#pragma unroll
  for (int r = 0; r < 8; ++r) acc[r] = bb;
  for (int k = 0; k < OUTD; ++k) {
    float w = W1[k * HIDD + t];
#pragma unroll
    for (int r = 0; r < 8; ++r) acc[r] += hr[r][k] * w;
  }
#pragma unroll
  for (int r = 0; r < 8; ++r) hid[r][t] = acc[r] > 0.f ? acc[r] : 0.f;
  __syncthreads();
  if (t < 96) {
    int r = t / 12, dd = t - r * 12;
    float a = b2[dd];
    for (int k = 0; k < HIDD; ++k) a += hid[r][k] * W2[k * 12 + dd];
    o[(n0 + r) * 12 + dd] = a;
  }
}

extern "C" void kernel_launch(void* const* d_in, const int* in_sizes, int n_in,
                              void* d_out, int out_size, void* d_ws, size_t ws_size,
                              hipStream_t stream) {
  (void)in_sizes; (void)n_in; (void)out_size; (void)ws_size;
  const float* x    = (const float*)d_in[0];
  const int*   eim  = (const int*)d_in[1];
  const int*   ei0  = (const int*)d_in[2];
  const float* ew0  = (const float*)d_in[3];
  const int*   ei1  = (const int*)d_in[4];
  const float* ew1  = (const float*)d_in[5];
  const int*   ei2  = (const int*)d_in[6];
  const float* ew2  = (const float*)d_in[7];
  const int*   ei3  = (const int*)d_in[8];
  const float* ew3  = (const float*)d_in[9];
  const int*   ei4  = (const int*)d_in[10];
  const float* ew4  = (const float*)d_in[11];
  const float* chebW0 = (const float*)d_in[12];
  const float* chebW1 = (const float*)d_in[13];
  const float* chebb  = (const float*)d_in[14];
  const float* lcW  = (const float*)d_in[15];
  const float* lcb  = (const float*)d_in[16];
  const float* att  = (const float*)d_in[17];
  const float* gzW  = (const float*)d_in[18];
  const float* gzb  = (const float*)d_in[19];
  const float* grW  = (const float*)d_in[20];
  const float* grb  = (const float*)d_in[21];
  const float* ghW  = (const float*)d_in[22];
  const float* ghb  = (const float*)d_in[23];
  const float* lzW  = (const float*)d_in[24];
  const float* lzb  = (const float*)d_in[25];
  const float* lrW  = (const float*)d_in[26];
  const float* lrb  = (const float*)d_in[27];
  const float* lhW  = (const float*)d_in[28];
  const float* lhb  = (const float*)d_in[29];
  const float* o1W  = (const float*)d_in[30];
  const float* o1b  = (const float*)d_in[31];
  const float* o2W  = (const float*)d_in[32];
  const float* o2b  = (const float*)d_in[33];

  float* ws = (float*)d_ws;
  float* out = (float*)d_out;
  float* o_out = out;                 // (N,12) flat
  float* H_out = out + NN * 12;       // (N,256) flat

  hipMemsetAsync(ws, 0, (size_t)WS_ZERO_END * sizeof(float), stream);
  probs_kernel<<<1, 64, 0, stream>>>(att, ws + WS_PROBS);
  deg_kernel<<<(EMAIN + 5 * EREG + 255) / 256, 256, 0, stream>>>(
      eim, ei0, ei1, ei2, ei3, ei4, ew0, ew1, ew2, ew3, ew4,
      ws + WS_DEGM, ws + WS_DEGR);
  dinv_kernel<<<(6 * NN + 255) / 256, 256, 0, stream>>>(
      ws + WS_DEGM, ws + WS_DEGR, ws + WS_DINVM, ws + WS_DINV2M, ws + WS_DINVR);
  norm_kernel<<<(EMAIN + 5 * EREG + 255) / 256, 256, 0, stream>>>(
      eim, ei0, ei1, ei2, ei3, ei4, ew0, ew1, ew2, ew3, ew4,
      ws + WS_DINVM, ws + WS_DINVR, ws + WS_NORMM, ws + WS_NORMR);
  scatter_kernel<<<((EMAIN + 5 * EREG) * 48) / 256, 256, 0, stream>>>(
      x, eim, ei0, ei1, ei2, ei3, ei4,
      ws + WS_NORMM, ws + WS_NORMR, ws + WS_AGGM, ws + WS_TX1);
  prep_kernel<<<1, 256, 0, stream>>>(
      chebW0, chebW1, chebb, lcW, lcb,
      gzW, gzb, grW, grb, ghW, ghb,
      lzW, lzb, lrW, lrb, lhW, lhb,
      ws + WS_MCAT, ws + WS_BIASH, ws + WS_AZ, ws + WS_AR, ws + WS_AH,
      ws + WS_BZ, ws + WS_BR, ws + WS_BH);
  prepT_kernel<<<1024, 128, 0, stream>>>(lzW, lrW, lhW, ws);
  gru_mfma_kernel<<<NN / 8, 512, 0, stream>>>(x, ws, H_out);
  head_kernel<<<NN / 8, 128, 0, stream>>>(H_out, o1W, o1b, o2W, o2b, o_out);
}

// Round 9
// 379.387 us; speedup vs baseline: 3.3751x; 1.2338x over previous
//
#include <hip/hip_runtime.h>
#include <cstddef>

#define NN    10000
#define PP    12
#define EMAIN 160000
#define EREG  40000
#define OUTD  256
#define HIDD  128

typedef __attribute__((ext_vector_type(8))) short bf16x8;
typedef __attribute__((ext_vector_type(4))) float f32x4;

// ---- workspace layout (float offsets) ----
enum : int {
  WS_PROBS    = 0,
  WS_DEGM     = 16,
  WS_DEGR     = WS_DEGM + NN,            // 5*NN
  WS_AGGM     = WS_DEGR + 5 * NN,        // NN*48
  WS_TX1      = WS_AGGM + NN * 48,       // 5*NN*48
  WS_ZERO_END = WS_TX1 + 5 * NN * 48,
  WS_DINVM    = WS_ZERO_END,
  WS_DINV2M   = WS_DINVM + NN,
  WS_DINVR    = WS_DINV2M + NN,          // 5*NN
  WS_NORMM    = WS_DINVR + 5 * NN,       // EMAIN
  WS_NORMR    = WS_NORMM + EMAIN,        // 5*EREG
  WS_MCAT     = WS_NORMR + 5 * EREG,     // 24*OUTD (fp32)
  WS_BIASH    = WS_MCAT + 24 * OUTD,
  WS_AZ       = WS_BIASH + OUTD,         // 4*OUTD  (Az,Ar,Ah contiguous)
  WS_AR       = WS_AZ + 4 * OUTD,
  WS_AH       = WS_AR + 4 * OUTD,
  WS_BZ       = WS_AH + 4 * OUTD,        // bz,br,bh contiguous
  WS_BR       = WS_BZ + OUTD,
  WS_BH       = WS_BR + OUTD,
  WS_MCT      = WS_BH + OUTD,            // 256*32 bf16 = 4096 floats
  WS_WZT      = WS_MCT + 4096,           // 256*288 bf16 = 36864 floats each
  WS_WRT      = WS_WZT + 36864,
  WS_WHT      = WS_WRT + 36864,
  WS_TOTAL    = WS_WHT + 36864
};

__device__ __forceinline__ float sigm(float v) { return 1.f / (1.f + __expf(-v)); }
__device__ __forceinline__ float tanh_f(float v) { float e = __expf(2.f * v); return 1.f - 2.f / (e + 1.f); }

// float -> bf16 bits, round-nearest-even
__device__ __forceinline__ short bf16b(float v) {
  unsigned x = __float_as_uint(v);
  unsigned r = (x + 0x7fffu + ((x >> 16) & 1u)) >> 16;
  return (short)r;
}
__device__ __forceinline__ float upk_lo(unsigned u) { return __uint_as_float(u << 16); }
__device__ __forceinline__ float upk_hi(unsigned u) { return __uint_as_float(u & 0xffff0000u); }
__device__ __forceinline__ unsigned pk2(float a, float b) {
  return (unsigned)(unsigned short)bf16b(a) | ((unsigned)(unsigned short)bf16b(b) << 16);
}

__device__ __forceinline__ const int* sel_i(int r, const int* a, const int* b, const int* c, const int* d, const int* e) {
  return r == 0 ? a : r == 1 ? b : r == 2 ? c : r == 3 ? d : e;
}
__device__ __forceinline__ const float* sel_f(int r, const float* a, const float* b, const float* c, const float* d, const float* e) {
  return r == 0 ? a : r == 1 ? b : r == 2 ? c : r == 3 ? d : e;
}

__global__ void probs_kernel(const float* __restrict__ att, float* __restrict__ probs) {
  if (threadIdx.x == 0 && blockIdx.x == 0) {
    float m = att[0];
    for (int i = 1; i < PP; ++i) m = fmaxf(m, att[i]);
    float e[PP]; float s = 0.f;
    for (int i = 0; i < PP; ++i) { e[i] = __expf(att[i] - m); s += e[i]; }
    float inv = 1.f / s;
    for (int i = 0; i < PP; ++i) probs[i] = e[i] * inv;
  }
}

__global__ void deg_kernel(const int* __restrict__ eim,
    const int* e0, const int* e1, const int* e2, const int* e3, const int* e4,
    const float* w0, const float* w1, const float* w2, const float* w3, const float* w4,
    float* __restrict__ degm, float* __restrict__ degr) {
  int g = blockIdx.x * 256 + threadIdx.x;
  if (g >= EMAIN + 5 * EREG) return;
  if (g < EMAIN) {
    atomicAdd(&degm[eim[EMAIN + g]], 1.0f);
  } else {
    int q = g - EMAIN;
    int r = q / EREG;
    int e = q - r * EREG;
    const int* ei = sel_i(r, e0, e1, e2, e3, e4);
    const float* w = sel_f(r, w0, w1, w2, w3, w4);
    atomicAdd(&degr[r * NN + ei[e]], w[e]);
  }
}

__global__ void dinv_kernel(const float* __restrict__ degm, const float* __restrict__ degr,
    float* __restrict__ dinvm, float* __restrict__ dinv2m, float* __restrict__ dinvr) {
  int g = blockIdx.x * 256 + threadIdx.x;
  if (g >= 6 * NN) return;
  if (g < NN) {
    float c = degm[g] + 1.0f;
    dinvm[g] = rsqrtf(c);
    dinv2m[g] = 1.0f / c;
  } else {
    int q = g - NN;
    float dv = degr[q];
    dinvr[q] = dv > 0.f ? rsqrtf(fmaxf(dv, 1e-12f)) : 0.f;
  }
}

__global__ void norm_kernel(const int* __restrict__ eim,
    const int* e0, const int* e1, const int* e2, const int* e3, const int* e4,
    const float* w0, const float* w1, const float* w2, const float* w3, const float* w4,
    const float* __restrict__ dinvm, const float* __restrict__ dinvr,
    float* __restrict__ normm, float* __restrict__ normr) {
  int g = blockIdx.x * 256 + threadIdx.x;
  if (g >= EMAIN + 5 * EREG) return;
  if (g < EMAIN) {
    int s = eim[g], d = eim[EMAIN + g];
    normm[g] = dinvm[s] * dinvm[d];
  } else {
    int q = g - EMAIN;
    int r = q / EREG;
    int e = q - r * EREG;
    const int* ei = sel_i(r, e0, e1, e2, e3, e4);
    const float* w = sel_f(r, w0, w1, w2, w3, w4);
    int s = ei[e], d = ei[EREG + e];
    normr[q] = -(dinvr[r * NN + s] * w[e] * dinvr[r * NN + d]);
  }
}

__global__ void scatter_kernel(const float* __restrict__ x,
    const int* __restrict__ eim,
    const int* e0, const int* e1, const int* e2, const int* e3, const int* e4,
    const float* __restrict__ normm, const float* __restrict__ normr,
    float* __restrict__ aggm, float* __restrict__ tx1) {
  int g = blockIdx.x * 256 + threadIdx.x;
  int eg = g / 48;
  int i = g - eg * 48;
  int s, d; float nv; float* out;
  if (eg < EMAIN) {
    s = eim[eg]; d = eim[EMAIN + eg]; nv = normm[eg]; out = aggm;
  } else {
    int q = eg - EMAIN;
    int r = q / EREG;
    int e = q - r * EREG;
    const int* ei = sel_i(r, e0, e1, e2, e3, e4);
    s = ei[e]; d = ei[EREG + e];
    nv = normr[q];
    out = tx1 + (size_t)r * (NN * 48);
  }
  atomicAdd(&out[d * 48 + i], nv * x[s * 48 + i]);
}

// parallel fold of small matrices (fp32), replacing the single-block prep_kernel
// (round-5 profile: 1-block prep = 142 us latency-serialized on one CU).
// grid = 128 blocks x 256 thr. Blocks 0..31: Mcat/biash (8 j-cols per block).
// Blocks 32..127: gate folds; g = (b-32)/32, 8 j-cols per block.
// Thread (jj,kk): jj = tid>>5 owns column j0+jj, kk = tid&31 strides K=256.
// 32-lane partial reduction via __shfl_xor (offsets 16..1 stay in-half).
__global__ __launch_bounds__(256) void prep_parallel_kernel(
    const float* __restrict__ W0, const float* __restrict__ W1, const float* __restrict__ chebb,
    const float* __restrict__ lcW, const float* __restrict__ lcb,
    const float* __restrict__ gzW, const float* __restrict__ gzb,
    const float* __restrict__ grW, const float* __restrict__ grb,
    const float* __restrict__ ghW, const float* __restrict__ ghb,
    const float* __restrict__ lzW, const float* __restrict__ lzb,
    const float* __restrict__ lrW, const float* __restrict__ lrb,
    const float* __restrict__ lhW, const float* __restrict__ lhb,
    float* __restrict__ ws) {
  const int b = blockIdx.x;
  const int tid = threadIdx.x;
  const int jj = tid >> 5;
  const int kk = tid & 31;

  if (b < 32) {
    const int j = b * 8 + jj;
    float m0[4] = {0, 0, 0, 0};
    float m1[5][4] = {};
    float bhh = 0.f;
    for (int k = kk; k < OUTD; k += 32) {
      float w1v[4];
#pragma unroll
      for (int f = 0; f < 4; ++f) w1v[f] = W1[f * OUTD + k];
      float s5 = 0.f;
#pragma unroll
      for (int r = 0; r < 5; ++r) {
        float wv = lcW[(r * OUTD + k) * OUTD + j];
        s5 += wv;
#pragma unroll
        for (int f = 0; f < 4; ++f) m1[r][f] += w1v[f] * wv;
      }
#pragma unroll
      for (int f = 0; f < 4; ++f) m0[f] += W0[f * OUTD + k] * s5;
      bhh += chebb[k] * s5;
    }
#pragma unroll
    for (int off = 16; off >= 1; off >>= 1) {
#pragma unroll
      for (int f = 0; f < 4; ++f) m0[f] += __shfl_xor(m0[f], off);
#pragma unroll
      for (int r = 0; r < 5; ++r)
#pragma unroll
        for (int f = 0; f < 4; ++f) m1[r][f] += __shfl_xor(m1[r][f], off);
      bhh += __shfl_xor(bhh, off);
    }
    if (kk == 0) {
      float* Mcat = ws + WS_MCAT;
#pragma unroll
      for (int f = 0; f < 4; ++f) Mcat[f * OUTD + j] = m0[f];
#pragma unroll
      for (int r = 0; r < 5; ++r)
#pragma unroll
        for (int f = 0; f < 4; ++f) Mcat[(4 + 4 * r + f) * OUTD + j] = m1[r][f];
      ws[WS_BIASH + j] = bhh + lcb[j];
    }
  } else {
    const int g = (b - 32) >> 5;
    const int j = ((b - 32) & 31) * 8 + jj;
    const float* gW = g == 0 ? gzW : g == 1 ? grW : ghW;
    const float* gb = g == 0 ? gzb : g == 1 ? grb : ghb;
    const float* lW = g == 0 ? lzW : g == 1 ? lrW : lhW;
    const float* lb = g == 0 ? lzb : g == 1 ? lrb : lhb;
    float a[4] = {0, 0, 0, 0};
    float vb = 0.f;
    for (int k = kk; k < OUTD; k += 32) {
      float wv = lW[k * OUTD + j];
#pragma unroll
      for (int f = 0; f < 4; ++f) a[f] += gW[f * OUTD + k] * wv;
      vb += gb[k] * wv;
    }
#pragma unroll
    for (int off = 16; off >= 1; off >>= 1) {
#pragma unroll
      for (int f = 0; f < 4; ++f) a[f] += __shfl_xor(a[f], off);
      vb += __shfl_xor(vb, off);
    }
    if (kk == 0) {
      float* A = ws + WS_AZ + g * (4 * OUTD);
#pragma unroll
      for (int f = 0; f < 4; ++f) A[f * OUTD + j] = a[f];
      ws[WS_BZ + g * OUTD + j] = vb + lb[j];
    }
  }
}

// build transposed bf16 weight panels: WT[col j][k 0..287]
//   k<256        -> bottom half of l?W (row 256+k, col j)
//   k in 280..283 -> A?fold[f=k-280][j]   (aggx contribution)
//   else          -> 0
// and McT[col j][k 0..31] (k<24 -> Mcat[k][j])
__global__ void prepT_kernel(
    const float* __restrict__ lzW, const float* __restrict__ lrW, const float* __restrict__ lhW,
    float* __restrict__ ws) {
  int bx = blockIdx.x;
  int g = bx >> 8;
  int j = bx & 255;
  if (g < 3) {
    const float* Wsrc = g == 0 ? lzW : g == 1 ? lrW : lhW;
    const float* Afold = ws + WS_AZ + g * (4 * OUTD);
    short* dst = (short*)(ws + (g == 0 ? WS_WZT : g == 1 ? WS_WRT : WS_WHT));
    for (int k = threadIdx.x; k < 288; k += 128) {
      float v = 0.f;
      if (k < 256) v = Wsrc[(256 + k) * OUTD + j];
      else if (k >= 280 && k < 284) v = Afold[(k - 280) * OUTD + j];
      dst[j * 288 + k] = bf16b(v);
    }
  } else {
    const float* Mcat = ws + WS_MCAT;
    short* mct = (short*)(ws + WS_MCT);
    for (int k = threadIdx.x; k < 32; k += 128) {
      float v = (k < 24) ? Mcat[k * OUTD + j] : 0.f;
      mct[j * 32 + k] = bf16b(v);
    }
  }
}

#define GATE_MFMA(WT) do {                                                          \
  _Pragma("unroll") for (int m_ = 0; m_ < 6; ++m_)                                  \
    _Pragma("unroll") for (int nt_ = 0; nt_ < 2; ++nt_)                             \
      acc[m_][nt_] = (f32x4){0.f, 0.f, 0.f, 0.f};                                   \
  _Pragma("unroll") for (int ks_ = 0; ks_ < 9; ++ks_) {                             \
    bf16x8 bfr_[2];                                                                 \
    _Pragma("unroll") for (int nt_ = 0; nt_ < 2; ++nt_)                             \
      bfr_[nt_] = *(const bf16x8*)((WT) + (size_t)(wcol + nt_ * 16 + lr) * 288 + ks_ * 32 + 8 * lg); \
    _Pragma("unroll") for (int m_ = 0; m_ < 6; ++m_) {                              \
      bf16x8 af_ = *(const bf16x8*)(&As[m_ * 16 + lr][ks_ * 32 + 8 * lg]);          \
      _Pragma("unroll") for (int nt_ = 0; nt_ < 2; ++nt_)                           \
        acc[m_][nt_] = __builtin_amdgcn_mfma_f32_16x16x32_bf16(af_, bfr_[nt_], acc[m_][nt_], 0, 0, 0); \
    }                                                                               \
  }                                                                                 \
} while (0)

// fused MFMA GRU: 8 nodes x 12 periods = 96 rows per block; 8 waves x 32 cols
__global__ __launch_bounds__(512, 2) void gru_mfma_kernel(
    const float* __restrict__ x,
    const float* __restrict__ ws,
    float* __restrict__ Hout) {
  const int n0 = blockIdx.x * 8;
  const int t = threadIdx.x;
  const int w = t >> 6;
  const int l = t & 63;
  const int lr = l & 15;
  const int lg = l >> 4;
  const int wcol = w * 32;

  __shared__ __align__(16) short As[96][296];   // rows: p*8+nl ; k: 0..255 h/hR, 256..287 U/aggx

  const float* aggm   = ws + WS_AGGM;
  const float* tx1    = ws + WS_TX1;
  const float* dinv2m = ws + WS_DINV2M;
  const float* biash  = ws + WS_BIASH;
  const float* bz     = ws + WS_BZ;
  const float* br     = ws + WS_BR;
  const float* bh     = ws + WS_BH;
  const float* probs  = ws + WS_PROBS;
  const short* McT = (const short*)(ws + WS_MCT);
  const short* WzT = (const short*)(ws + WS_WZT);
  const short* WrT = (const short*)(ws + WS_WRT);
  const short* WhT = (const short*)(ws + WS_WHT);

  // ---- stage U (bf16) into As[row][256..287]
  for (int idx = t; idx < 96 * 32; idx += 512) {
    int row = idx >> 5, s = idx & 31;
    int p = row >> 3, nl = row & 7, n = n0 + nl;
    float v = 0.f;
    if (s < 4) {
      v = x[n * 48 + s * 12 + p];
    } else if (s < 24) {
      int q = s - 4; int r = q >> 2; int f = q & 3;
      v = tx1[(size_t)(r * NN + n) * 48 + f * 12 + p];
    } else if (s < 28) {
      int f = s - 24;
      v = aggm[n * 48 + f * 12 + p] + dinv2m[n] * x[n * 48 + f * 12 + p];
    }
    As[row][256 + s] = bf16b(v);
  }
  __syncthreads();

  f32x4 acc[6][2];

  // ---- h = leaky_relu(U @ Mcat + biash)
  {
    bf16x8 bm[2];
#pragma unroll
    for (int nt = 0; nt < 2; ++nt)
      bm[nt] = *(const bf16x8*)(McT + (size_t)(wcol + nt * 16 + lr) * 32 + 8 * lg);
    const f32x4 zf = {0.f, 0.f, 0.f, 0.f};
#pragma unroll
    for (int m = 0; m < 6; ++m) {
      bf16x8 af = *(const bf16x8*)(&As[m * 16 + lr][256 + 8 * lg]);
#pragma unroll
      for (int nt = 0; nt < 2; ++nt)
        acc[m][nt] = __builtin_amdgcn_mfma_f32_16x16x32_bf16(af, bm[nt], zf, 0, 0, 0);
    }
  }
  unsigned hp[6][2][2];
#pragma unroll
  for (int nt = 0; nt < 2; ++nt) {
    int col = wcol + nt * 16 + lr;
    float bb = biash[col];
#pragma unroll
    for (int m = 0; m < 6; ++m) {
      f32x4 a = acc[m][nt];
      int rmb = m * 16 + 4 * lg;
      float v0 = a[0] + bb; v0 = v0 > 0.f ? v0 : 0.01f * v0;
      float v1 = a[1] + bb; v1 = v1 > 0.f ? v1 : 0.01f * v1;
      float v2 = a[2] + bb; v2 = v2 > 0.f ? v2 : 0.01f * v2;
      float v3 = a[3] + bb; v3 = v3 > 0.f ? v3 : 0.01f * v3;
      short s0 = bf16b(v0), s1 = bf16b(v1), s2 = bf16b(v2), s3 = bf16b(v3);
      As[rmb + 0][col] = s0; As[rmb + 1][col] = s1;
      As[rmb + 2][col] = s2; As[rmb + 3][col] = s3;
      hp[m][nt][0] = (unsigned)(unsigned short)s0 | ((unsigned)(unsigned short)s1 << 16);
      hp[m][nt][1] = (unsigned)(unsigned short)s2 | ((unsigned)(unsigned short)s3 << 16);
    }
  }
  __syncthreads();

  // ---- Z
  GATE_MFMA(WzT);
  unsigned zp[6][2][2];
#pragma unroll
  for (int nt = 0; nt < 2; ++nt) {
    float bb = bz[wcol + nt * 16 + lr];
#pragma unroll
    for (int m = 0; m < 6; ++m) {
      f32x4 a = acc[m][nt];
      zp[m][nt][0] = pk2(sigm(a[0] + bb), sigm(a[1] + bb));
      zp[m][nt][1] = pk2(sigm(a[2] + bb), sigm(a[3] + bb));
    }
  }

  // ---- R ; overwrite As k<256 with h*R
  GATE_MFMA(WrT);
  __syncthreads();
#pragma unroll
  for (int nt = 0; nt < 2; ++nt) {
    int col = wcol + nt * 16 + lr;
    float bb = br[col];
#pragma unroll
    for (int m = 0; m < 6; ++m) {
      f32x4 a = acc[m][nt];
      int rmb = m * 16 + 4 * lg;
      As[rmb + 0][col] = bf16b(upk_lo(hp[m][nt][0]) * sigm(a[0] + bb));
      As[rmb + 1][col] = bf16b(upk_hi(hp[m][nt][0]) * sigm(a[1] + bb));
      As[rmb + 2][col] = bf16b(upk_lo(hp[m][nt][1]) * sigm(a[2] + bb));
      As[rmb + 3][col] = bf16b(upk_hi(hp[m][nt][1]) * sigm(a[3] + bb));
    }
  }
  __syncthreads();

  // ---- Ht ; final combine + attention-weighted p-reduction
  GATE_MFMA(WhT);
  float pr[6];
#pragma unroll
  for (int m = 0; m < 6; ++m) pr[m] = probs[2 * m + (lg >> 1)];
  float wsum[2][4];
#pragma unroll
  for (int nt = 0; nt < 2; ++nt)
#pragma unroll
    for (int q = 0; q < 4; ++q) wsum[nt][q] = 0.f;
#pragma unroll
  for (int nt = 0; nt < 2; ++nt) {
    int col = wcol + nt * 16 + lr;
    float bb = bh[col];
#pragma unroll
    for (int m = 0; m < 6; ++m) {
      f32x4 a = acc[m][nt];
      float hv0 = upk_lo(hp[m][nt][0]), hv1 = upk_hi(hp[m][nt][0]);
      float hv2 = upk_lo(hp[m][nt][1]), hv3 = upk_hi(hp[m][nt][1]);
      float zv0 = upk_lo(zp[m][nt][0]), zv1 = upk_hi(zp[m][nt][0]);
      float zv2 = upk_lo(zp[m][nt][1]), zv3 = upk_hi(zp[m][nt][1]);
      float t0 = tanh_f(a[0] + bb);
      float t1 = tanh_f(a[1] + bb);
      float t2 = tanh_f(a[2] + bb);
      float t3 = tanh_f(a[3] + bb);
      wsum[nt][0] += pr[m] * (zv0 * hv0 + (1.f - zv0) * t0);
      wsum[nt][1] += pr[m] * (zv1 * hv1 + (1.f - zv1) * t1);
      wsum[nt][2] += pr[m] * (zv2 * hv2 + (1.f - zv2) * t2);
      wsum[nt][3] += pr[m] * (zv3 * hv3 + (1.f - zv3) * t3);
    }
  }
#pragma unroll
  for (int nt = 0; nt < 2; ++nt)
#pragma unroll
    for (int q = 0; q < 4; ++q) {
      float tot = wsum[nt][q] + __shfl_xor(wsum[nt][q], 32);
      if (lg < 2)
        Hout[(size_t)(n0 + 4 * lg + q) * OUTD + wcol + nt * 16 + lr] = tot;
    }
}

// o = relu(relu(H) @ out1_W + b1) @ out2_W + b2 ; 8 nodes per block
__global__ __launch_bounds__(128) void head_kernel(
    const float* __restrict__ H,
    const float* __restrict__ W1, const float* __restrict__ b1,
    const float* __restrict__ W2, const float* __restrict__ b2,
    float* __restrict__ o) {
  const int n0 = blockIdx.x * 8;
  const int t = threadIdx.x;
  __shared__ float hr[8][OUTD];
  __shared__ float hid[8][130];
  for (int idx = t; idx < 8 * OUTD; idx += 128) {
    int r = idx >> 8, c = idx & 255;
    float v = H[(n0 + r) * OUTD + c];
    hr[r][c] = v > 0.f ? v : 0.f;
  }
  __syncthreads();
  float acc[8];
  float bb = b1[t];
#pragma unroll
  for (int r = 0; r < 8; ++r) acc[r] = bb;
  for (int k = 0; k < OUTD; ++k) {
    float w = W1[k * HIDD + t];
#pragma unroll
    for (int r = 0; r < 8; ++r) acc[r] += hr[r][k] * w;
  }
#pragma unroll
  for (int r = 0; r < 8; ++r) hid[r][t] = acc[r] > 0.f ? acc[r] : 0.f;
  __syncthreads();
  if (t < 96) {
    int r = t / 12, dd = t - r * 12;
    float a = b2[dd];
    for (int k = 0; k < HIDD; ++k) a += hid[r][k] * W2[k * 12 + dd];
    o[(n0 + r) * 12 + dd] = a;
  }
}

extern "C" void kernel_launch(void* const* d_in, const int* in_sizes, int n_in,
                              void* d_out, int out_size, void* d_ws, size_t ws_size,
                              hipStream_t stream) {
  (void)in_sizes; (void)n_in; (void)out_size; (void)ws_size;
  const float* x    = (const float*)d_in[0];
  const int*   eim  = (const int*)d_in[1];
  const int*   ei0  = (const int*)d_in[2];
  const float* ew0  = (const float*)d_in[3];
  const int*   ei1  = (const int*)d_in[4];
  const float* ew1  = (const float*)d_in[5];
  const int*   ei2  = (const int*)d_in[6];
  const float* ew2  = (const float*)d_in[7];
  const int*   ei3  = (const int*)d_in[8];
  const float* ew3  = (const float*)d_in[9];
  const int*   ei4  = (const int*)d_in[10];
  const float* ew4  = (const float*)d_in[11];
  const float* chebW0 = (const float*)d_in[12];
  const float* chebW1 = (const float*)d_in[13];
  const float* chebb  = (const float*)d_in[14];
  const float* lcW  = (const float*)d_in[15];
  const float* lcb  = (const float*)d_in[16];
  const float* att  = (const float*)d_in[17];
  const float* gzW  = (const float*)d_in[18];
  const float* gzb  = (const float*)d_in[19];
  const float* grW  = (const float*)d_in[20];
  const float* grb  = (const float*)d_in[21];
  const float* ghW  = (const float*)d_in[22];
  const float* ghb  = (const float*)d_in[23];
  const float* lzW  = (const float*)d_in[24];
  const float* lzb  = (const float*)d_in[25];
  const float* lrW  = (const float*)d_in[26];
  const float* lrb  = (const float*)d_in[27];
  const float* lhW  = (const float*)d_in[28];
  const float* lhb  = (const float*)d_in[29];
  const float* o1W  = (const float*)d_in[30];
  const float* o1b  = (const float*)d_in[31];
  const float* o2W  = (const float*)d_in[32];
  const float* o2b  = (const float*)d_in[33];

  float* ws = (float*)d_ws;
  float* out = (float*)d_out;
  float* o_out = out;                 // (N,12) flat
  float* H_out = out + NN * 12;       // (N,256) flat

  hipMemsetAsync(ws, 0, (size_t)WS_ZERO_END * sizeof(float), stream);
  probs_kernel<<<1, 64, 0, stream>>>(att, ws + WS_PROBS);
  deg_kernel<<<(EMAIN + 5 * EREG + 255) / 256, 256, 0, stream>>>(
      eim, ei0, ei1, ei2, ei3, ei4, ew0, ew1, ew2, ew3, ew4,
      ws + WS_DEGM, ws + WS_DEGR);
  dinv_kernel<<<(6 * NN + 255) / 256, 256, 0, stream>>>(
      ws + WS_DEGM, ws + WS_DEGR, ws + WS_DINVM, ws + WS_DINV2M, ws + WS_DINVR);
  norm_kernel<<<(EMAIN + 5 * EREG + 255) / 256, 256, 0, stream>>>(
      eim, ei0, ei1, ei2, ei3, ei4, ew0, ew1, ew2, ew3, ew4,
      ws + WS_DINVM, ws + WS_DINVR, ws + WS_NORMM, ws + WS_NORMR);
  scatter_kernel<<<((EMAIN + 5 * EREG) * 48) / 256, 256, 0, stream>>>(
      x, eim, ei0, ei1, ei2, ei3, ei4,
      ws + WS_NORMM, ws + WS_NORMR, ws + WS_AGGM, ws + WS_TX1);
  prep_parallel_kernel<<<128, 256, 0, stream>>>(
      chebW0, chebW1, chebb, lcW, lcb,
      gzW, gzb, grW, grb, ghW, ghb,
      lzW, lzb, lrW, lrb, lhW, lhb,
      ws);
  prepT_kernel<<<1024, 128, 0, stream>>>(lzW, lrW, lhW, ws);
  gru_mfma_kernel<<<NN / 8, 512, 0, stream>>>(x, ws, H_out);
  head_kernel<<<NN / 8, 128, 0, stream>>>(H_out, o1W, o1b, o2W, o2b, o_out);
}

// Round 13
// 374.253 us; speedup vs baseline: 3.4214x; 1.0137x over previous
//
#include <hip/hip_runtime.h>
#include <hip/hip_bf16.h>
#include <cstddef>

#define NN    10000
#define PP    12
#define EMAIN 160000
#define EREG  40000
#define OUTD  256
#define HIDD  128

typedef __attribute__((ext_vector_type(8))) short bf16x8;
typedef __attribute__((ext_vector_type(4))) float f32x4;

// ---- workspace layout (float offsets) ----
enum : int {
  WS_PROBS    = 0,
  WS_DEGM     = 16,
  WS_DEGR     = WS_DEGM + NN,            // 5*NN
  WS_AGGM     = WS_DEGR + 5 * NN,        // NN*48
  WS_TX1      = WS_AGGM + NN * 48,       // 5*NN*48
  WS_ZERO_END = WS_TX1 + 5 * NN * 48,
  WS_DINVM    = WS_ZERO_END,
  WS_DINV2M   = WS_DINVM + NN,
  WS_DINVR    = WS_DINV2M + NN,          // 5*NN
  WS_NORMM    = WS_DINVR + 5 * NN,       // EMAIN
  WS_NORMR    = WS_NORMM + EMAIN,        // 5*EREG
  WS_MCAT     = WS_NORMR + 5 * EREG,     // 24*OUTD (fp32)
  WS_BIASH    = WS_MCAT + 24 * OUTD,
  WS_AZ       = WS_BIASH + OUTD,         // 4*OUTD  (Az,Ar,Ah contiguous)
  WS_AR       = WS_AZ + 4 * OUTD,
  WS_AH       = WS_AR + 4 * OUTD,
  WS_BZ       = WS_AH + 4 * OUTD,        // bz,br,bh contiguous
  WS_BR       = WS_BZ + OUTD,
  WS_BH       = WS_BR + OUTD,
  WS_MCT      = WS_BH + OUTD,            // 256*32 bf16 = 4096 floats
  WS_WZT      = WS_MCT + 4096,           // 256*288 bf16 = 36864 floats each
  WS_WRT      = WS_WZT + 36864,
  WS_WHT      = WS_WRT + 36864,
  WS_TOTAL    = WS_WHT + 36864
};

__device__ __forceinline__ float sigm(float v) { return 1.f / (1.f + __expf(-v)); }
__device__ __forceinline__ float tanh_f(float v) { float e = __expf(2.f * v); return 1.f - 2.f / (e + 1.f); }

// native HW bf16 conversions (compiler emits v_cvt_pk_bf16_f32; manual bit-math
// RNE defeats the pattern-match and costs ~4 VALU ops per value — round-9 lesson).
// NB: __hip_bfloat16/2 are NOT trivially copyable (round-12 compile error) —
// use __builtin_memcpy, not __builtin_bit_cast.
__device__ __forceinline__ short bf16c(float v) {
  __hip_bfloat16 h = __float2bfloat16(v);
  short r;
  __builtin_memcpy(&r, &h, sizeof(r));
  return r;
}
__device__ __forceinline__ unsigned cvt2(float a, float b) {
  __hip_bfloat162 h2 = __float22bfloat162_rn(make_float2(a, b));
  unsigned r;
  __builtin_memcpy(&r, &h2, sizeof(r));
  return r;
}
__device__ __forceinline__ float upk_lo(unsigned u) { return __uint_as_float(u << 16); }
__device__ __forceinline__ float upk_hi(unsigned u) { return __uint_as_float(u & 0xffff0000u); }

__device__ __forceinline__ const int* sel_i(int r, const int* a, const int* b, const int* c, const int* d, const int* e) {
  return r == 0 ? a : r == 1 ? b : r == 2 ? c : r == 3 ? d : e;
}
__device__ __forceinline__ const float* sel_f(int r, const float* a, const float* b, const float* c, const float* d, const float* e) {
  return r == 0 ? a : r == 1 ? b : r == 2 ? c : r == 3 ? d : e;
}

__global__ void probs_kernel(const float* __restrict__ att, float* __restrict__ probs) {
  if (threadIdx.x == 0 && blockIdx.x == 0) {
    float m = att[0];
    for (int i = 1; i < PP; ++i) m = fmaxf(m, att[i]);
    float e[PP]; float s = 0.f;
    for (int i = 0; i < PP; ++i) { e[i] = __expf(att[i] - m); s += e[i]; }
    float inv = 1.f / s;
    for (int i = 0; i < PP; ++i) probs[i] = e[i] * inv;
  }
}

__global__ void deg_kernel(const int* __restrict__ eim,
    const int* e0, const int* e1, const int* e2, const int* e3, const int* e4,
    const float* w0, const float* w1, const float* w2, const float* w3, const float* w4,
    float* __restrict__ degm, float* __restrict__ degr) {
  int g = blockIdx.x * 256 + threadIdx.x;
  if (g >= EMAIN + 5 * EREG) return;
  if (g < EMAIN) {
    atomicAdd(&degm[eim[EMAIN + g]], 1.0f);
  } else {
    int q = g - EMAIN;
    int r = q / EREG;
    int e = q - r * EREG;
    const int* ei = sel_i(r, e0, e1, e2, e3, e4);
    const float* w = sel_f(r, w0, w1, w2, w3, w4);
    atomicAdd(&degr[r * NN + ei[e]], w[e]);
  }
}

__global__ void dinv_kernel(const float* __restrict__ degm, const float* __restrict__ degr,
    float* __restrict__ dinvm, float* __restrict__ dinv2m, float* __restrict__ dinvr) {
  int g = blockIdx.x * 256 + threadIdx.x;
  if (g >= 6 * NN) return;
  if (g < NN) {
    float c = degm[g] + 1.0f;
    dinvm[g] = rsqrtf(c);
    dinv2m[g] = 1.0f / c;
  } else {
    int q = g - NN;
    float dv = degr[q];
    dinvr[q] = dv > 0.f ? rsqrtf(fmaxf(dv, 1e-12f)) : 0.f;
  }
}

__global__ void norm_kernel(const int* __restrict__ eim,
    const int* e0, const int* e1, const int* e2, const int* e3, const int* e4,
    const float* w0, const float* w1, const float* w2, const float* w3, const float* w4,
    const float* __restrict__ dinvm, const float* __restrict__ dinvr,
    float* __restrict__ normm, float* __restrict__ normr) {
  int g = blockIdx.x * 256 + threadIdx.x;
  if (g >= EMAIN + 5 * EREG) return;
  if (g < EMAIN) {
    int s = eim[g], d = eim[EMAIN + g];
    normm[g] = dinvm[s] * dinvm[d];
  } else {
    int q = g - EMAIN;
    int r = q / EREG;
    int e = q - r * EREG;
    const int* ei = sel_i(r, e0, e1, e2, e3, e4);
    const float* w = sel_f(r, w0, w1, w2, w3, w4);
    int s = ei[e], d = ei[EREG + e];
    normr[q] = -(dinvr[r * NN + s] * w[e] * dinvr[r * NN + d]);
  }
}

__global__ void scatter_kernel(const float* __restrict__ x,
    const int* __restrict__ eim,
    const int* e0, const int* e1, const int* e2, const int* e3, const int* e4,
    const float* __restrict__ normm, const float* __restrict__ normr,
    float* __restrict__ aggm, float* __restrict__ tx1) {
  int g = blockIdx.x * 256 + threadIdx.x;
  int eg = g / 48;
  int i = g - eg * 48;
  int s, d; float nv; float* out;
  if (eg < EMAIN) {
    s = eim[eg]; d = eim[EMAIN + eg]; nv = normm[eg]; out = aggm;
  } else {
    int q = eg - EMAIN;
    int r = q / EREG;
    int e = q - r * EREG;
    const int* ei = sel_i(r, e0, e1, e2, e3, e4);
    s = ei[e]; d = ei[EREG + e];
    nv = normr[q];
    out = tx1 + (size_t)r * (NN * 48);
  }
  atomicAdd(&out[d * 48 + i], nv * x[s * 48 + i]);
}

// parallel fold of small matrices (fp32). 128 blocks x 256 thr; see round-6 notes.
__global__ __launch_bounds__(256) void prep_parallel_kernel(
    const float* __restrict__ W0, const float* __restrict__ W1, const float* __restrict__ chebb,
    const float* __restrict__ lcW, const float* __restrict__ lcb,
    const float* __restrict__ gzW, const float* __restrict__ gzb,
    const float* __restrict__ grW, const float* __restrict__ grb,
    const float* __restrict__ ghW, const float* __restrict__ ghb,
    const float* __restrict__ lzW, const float* __restrict__ lzb,
    const float* __restrict__ lrW, const float* __restrict__ lrb,
    const float* __restrict__ lhW, const float* __restrict__ lhb,
    float* __restrict__ ws) {
  const int b = blockIdx.x;
  const int tid = threadIdx.x;
  const int jj = tid >> 5;
  const int kk = tid & 31;

  if (b < 32) {
    const int j = b * 8 + jj;
    float m0[4] = {0, 0, 0, 0};
    float m1[5][4] = {};
    float bhh = 0.f;
    for (int k = kk; k < OUTD; k += 32) {
      float w1v[4];
#pragma unroll
      for (int f = 0; f < 4; ++f) w1v[f] = W1[f * OUTD + k];
      float s5 = 0.f;
#pragma unroll
      for (int r = 0; r < 5; ++r) {
        float wv = lcW[(r * OUTD + k) * OUTD + j];
        s5 += wv;
#pragma unroll
        for (int f = 0; f < 4; ++f) m1[r][f] += w1v[f] * wv;
      }
#pragma unroll
      for (int f = 0; f < 4; ++f) m0[f] += W0[f * OUTD + k] * s5;
      bhh += chebb[k] * s5;
    }
#pragma unroll
    for (int off = 16; off >= 1; off >>= 1) {
#pragma unroll
      for (int f = 0; f < 4; ++f) m0[f] += __shfl_xor(m0[f], off);
#pragma unroll
      for (int r = 0; r < 5; ++r)
#pragma unroll
        for (int f = 0; f < 4; ++f) m1[r][f] += __shfl_xor(m1[r][f], off);
      bhh += __shfl_xor(bhh, off);
    }
    if (kk == 0) {
      float* Mcat = ws + WS_MCAT;
#pragma unroll
      for (int f = 0; f < 4; ++f) Mcat[f * OUTD + j] = m0[f];
#pragma unroll
      for (int r = 0; r < 5; ++r)
#pragma unroll
        for (int f = 0; f < 4; ++f) Mcat[(4 + 4 * r + f) * OUTD + j] = m1[r][f];
      ws[WS_BIASH + j] = bhh + lcb[j];
    }
  } else {
    const int g = (b - 32) >> 5;
    const int j = ((b - 32) & 31) * 8 + jj;
    const float* gW = g == 0 ? gzW : g == 1 ? grW : ghW;
    const float* gb = g == 0 ? gzb : g == 1 ? grb : ghb;
    const float* lW = g == 0 ? lzW : g == 1 ? lrW : lhW;
    const float* lb = g == 0 ? lzb : g == 1 ? lrb : lhb;
    float a[4] = {0, 0, 0, 0};
    float vb = 0.f;
    for (int k = kk; k < OUTD; k += 32) {
      float wv = lW[k * OUTD + j];
#pragma unroll
      for (int f = 0; f < 4; ++f) a[f] += gW[f * OUTD + k] * wv;
      vb += gb[k] * wv;
    }
#pragma unroll
    for (int off = 16; off >= 1; off >>= 1) {
#pragma unroll
      for (int f = 0; f < 4; ++f) a[f] += __shfl_xor(a[f], off);
      vb += __shfl_xor(vb, off);
    }
    if (kk == 0) {
      float* A = ws + WS_AZ + g * (4 * OUTD);
#pragma unroll
      for (int f = 0; f < 4; ++f) A[f * OUTD + j] = a[f];
      ws[WS_BZ + g * OUTD + j] = vb + lb[j];
    }
  }
}

// build transposed bf16 weight panels (see round-4 notes)
__global__ void prepT_kernel(
    const float* __restrict__ lzW, const float* __restrict__ lrW, const float* __restrict__ lhW,
    float* __restrict__ ws) {
  int bx = blockIdx.x;
  int g = bx >> 8;
  int j = bx & 255;
  if (g < 3) {
    const float* Wsrc = g == 0 ? lzW : g == 1 ? lrW : lhW;
    const float* Afold = ws + WS_AZ + g * (4 * OUTD);
    short* dst = (short*)(ws + (g == 0 ? WS_WZT : g == 1 ? WS_WRT : WS_WHT));
    for (int k = threadIdx.x; k < 288; k += 128) {
      float v = 0.f;
      if (k < 256) v = Wsrc[(256 + k) * OUTD + j];
      else if (k >= 280 && k < 284) v = Afold[(k - 280) * OUTD + j];
      dst[j * 288 + k] = bf16c(v);
    }
  } else {
    const float* Mcat = ws + WS_MCAT;
    short* mct = (short*)(ws + WS_MCT);
    for (int k = threadIdx.x; k < 32; k += 128) {
      float v = (k < 24) ? Mcat[k * OUTD + j] : 0.f;
      mct[j * 32 + k] = bf16c(v);
    }
  }
}

#define GATE_MFMA(WT) do {                                                          \
  _Pragma("unroll") for (int m_ = 0; m_ < 6; ++m_)                                  \
    _Pragma("unroll") for (int nt_ = 0; nt_ < 2; ++nt_)                             \
      acc[m_][nt_] = (f32x4){0.f, 0.f, 0.f, 0.f};                                   \
  _Pragma("unroll") for (int ks_ = 0; ks_ < 9; ++ks_) {                             \
    bf16x8 bfr_[2];                                                                 \
    _Pragma("unroll") for (int nt_ = 0; nt_ < 2; ++nt_)                             \
      bfr_[nt_] = *(const bf16x8*)((WT) + (size_t)(wcol + nt_ * 16 + lr) * 288 + ks_ * 32 + 8 * lg); \
    _Pragma("unroll") for (int m_ = 0; m_ < 6; ++m_) {                              \
      bf16x8 af_ = *(const bf16x8*)(&As[m_ * 16 + lr][ks_ * 32 + 8 * lg]);          \
      _Pragma("unroll") for (int nt_ = 0; nt_ < 2; ++nt_)                           \
        acc[m_][nt_] = __builtin_amdgcn_mfma_f32_16x16x32_bf16(af_, bfr_[nt_], acc[m_][nt_], 0, 0, 0); \
    }                                                                               \
  }                                                                                 \
} while (0)

// fused MFMA GRU: 8 nodes x 12 periods = 96 rows per block; 8 waves x 32 cols
__global__ __launch_bounds__(512, 2) void gru_mfma_kernel(
    const float* __restrict__ x,
    const float* __restrict__ ws,
    float* __restrict__ Hout) {
  const int n0 = blockIdx.x * 8;
  const int t = threadIdx.x;
  const int w = t >> 6;
  const int l = t & 63;
  const int lr = l & 15;
  const int lg = l >> 4;
  const int wcol = w * 32;

  __shared__ __align__(16) short As[96][296];   // rows: p*8+nl ; k: 0..255 h/hR, 256..287 U/aggx

  const float* aggm   = ws + WS_AGGM;
  const float* tx1    = ws + WS_TX1;
  const float* dinv2m = ws + WS_DINV2M;
  const float* biash  = ws + WS_BIASH;
  const float* bz     = ws + WS_BZ;
  const float* br     = ws + WS_BR;
  const float* bh     = ws + WS_BH;
  const float* probs  = ws + WS_PROBS;
  const short* McT = (const short*)(ws + WS_MCT);
  const short* WzT = (const short*)(ws + WS_WZT);
  const short* WrT = (const short*)(ws + WS_WRT);
  const short* WhT = (const short*)(ws + WS_WHT);

  // ---- stage U (bf16) into As[row][256..287]
  for (int idx = t; idx < 96 * 32; idx += 512) {
    int row = idx >> 5, s = idx & 31;
    int p = row >> 3, nl = row & 7, n = n0 + nl;
    float v = 0.f;
    if (s < 4) {
      v = x[n * 48 + s * 12 + p];
    } else if (s < 24) {
      int q = s - 4; int r = q >> 2; int f = q & 3;
      v = tx1[(size_t)(r * NN + n) * 48 + f * 12 + p];
    } else if (s < 28) {
      int f = s - 24;
      v = aggm[n * 48 + f * 12 + p] + dinv2m[n] * x[n * 48 + f * 12 + p];
    }
    As[row][256 + s] = bf16c(v);
  }
  __syncthreads();

  f32x4 acc[6][2];

  // ---- h = leaky_relu(U @ Mcat + biash)
  {
    bf16x8 bm[2];
#pragma unroll
    for (int nt = 0; nt < 2; ++nt)
      bm[nt] = *(const bf16x8*)(McT + (size_t)(wcol + nt * 16 + lr) * 32 + 8 * lg);
    const f32x4 zf = {0.f, 0.f, 0.f, 0.f};
#pragma unroll
    for (int m = 0; m < 6; ++m) {
      bf16x8 af = *(const bf16x8*)(&As[m * 16 + lr][256 + 8 * lg]);
#pragma unroll
      for (int nt = 0; nt < 2; ++nt)
        acc[m][nt] = __builtin_amdgcn_mfma_f32_16x16x32_bf16(af, bm[nt], zf, 0, 0, 0);
    }
  }
  unsigned hp[6][2][2];
#pragma unroll
  for (int nt = 0; nt < 2; ++nt) {
    int col = wcol + nt * 16 + lr;
    float bb = biash[col];
#pragma unroll
    for (int m = 0; m < 6; ++m) {
      f32x4 a = acc[m][nt];
      int rmb = m * 16 + 4 * lg;
      float v0 = a[0] + bb; v0 = fmaxf(v0, 0.01f * v0);   // leaky_relu
      float v1 = a[1] + bb; v1 = fmaxf(v1, 0.01f * v1);
      float v2 = a[2] + bb; v2 = fmaxf(v2, 0.01f * v2);
      float v3 = a[3] + bb; v3 = fmaxf(v3, 0.01f * v3);
      unsigned u01 = cvt2(v0, v1);
      unsigned u23 = cvt2(v2, v3);
      As[rmb + 0][col] = (short)(u01 & 0xffffu);
      As[rmb + 1][col] = (short)(u01 >> 16);
      As[rmb + 2][col] = (short)(u23 & 0xffffu);
      As[rmb + 3][col] = (short)(u23 >> 16);
      hp[m][nt][0] = u01;
      hp[m][nt][1] = u23;
    }
  }
  __syncthreads();

  // ---- Z
  GATE_MFMA(WzT);
  unsigned zp[6][2][2];
#pragma unroll
  for (int nt = 0; nt < 2; ++nt) {
    float bb = bz[wcol + nt * 16 + lr];
#pragma unroll
    for (int m = 0; m < 6; ++m) {
      f32x4 a = acc[m][nt];
      zp[m][nt][0] = cvt2(sigm(a[0] + bb), sigm(a[1] + bb));
      zp[m][nt][1] = cvt2(sigm(a[2] + bb), sigm(a[3] + bb));
    }
  }

  // ---- R ; overwrite As k<256 with h*R
  GATE_MFMA(WrT);
  __syncthreads();
#pragma unroll
  for (int nt = 0; nt < 2; ++nt) {
    int col = wcol + nt * 16 + lr;
    float bb = br[col];
#pragma unroll
    for (int m = 0; m < 6; ++m) {
      f32x4 a = acc[m][nt];
      int rmb = m * 16 + 4 * lg;
      unsigned u01 = cvt2(upk_lo(hp[m][nt][0]) * sigm(a[0] + bb),
                          upk_hi(hp[m][nt][0]) * sigm(a[1] + bb));
      unsigned u23 = cvt2(upk_lo(hp[m][nt][1]) * sigm(a[2] + bb),
                          upk_hi(hp[m][nt][1]) * sigm(a[3] + bb));
      As[rmb + 0][col] = (short)(u01 & 0xffffu);
      As[rmb + 1][col] = (short)(u01 >> 16);
      As[rmb + 2][col] = (short)(u23 & 0xffffu);
      As[rmb + 3][col] = (short)(u23 >> 16);
    }
  }
  __syncthreads();

  // ---- Ht ; final combine + attention-weighted p-reduction
  GATE_MFMA(WhT);
  float pr[6];
#pragma unroll
  for (int m = 0; m < 6; ++m) pr[m] = probs[2 * m + (lg >> 1)];
  float wsum[2][4];
#pragma unroll
  for (int nt = 0; nt < 2; ++nt)
#pragma unroll
    for (int q = 0; q < 4; ++q) wsum[nt][q] = 0.f;
#pragma unroll
  for (int nt = 0; nt < 2; ++nt) {
    int col = wcol + nt * 16 + lr;
    float bb = bh[col];
#pragma unroll
    for (int m = 0; m < 6; ++m) {
      f32x4 a = acc[m][nt];
      float hv0 = upk_lo(hp[m][nt][0]), hv1 = upk_hi(hp[m][nt][0]);
      float hv2 = upk_lo(hp[m][nt][1]), hv3 = upk_hi(hp[m][nt][1]);
      float zv0 = upk_lo(zp[m][nt][0]), zv1 = upk_hi(zp[m][nt][0]);
      float zv2 = upk_lo(zp[m][nt][1]), zv3 = upk_hi(zp[m][nt][1]);
      float t0 = tanh_f(a[0] + bb);
      float t1 = tanh_f(a[1] + bb);
      float t2 = tanh_f(a[2] + bb);
      float t3 = tanh_f(a[3] + bb);
      // z*h + (1-z)*t  ==  t + z*(h-t)
      wsum[nt][0] += pr[m] * (t0 + zv0 * (hv0 - t0));
      wsum[nt][1] += pr[m] * (t1 + zv1 * (hv1 - t1));
      wsum[nt][2] += pr[m] * (t2 + zv2 * (hv2 - t2));
      wsum[nt][3] += pr[m] * (t3 + zv3 * (hv3 - t3));
    }
  }
#pragma unroll
  for (int nt = 0; nt < 2; ++nt)
#pragma unroll
    for (int q = 0; q < 4; ++q) {
      float tot = wsum[nt][q] + __shfl_xor(wsum[nt][q], 32);
      if (lg < 2)
        Hout[(size_t)(n0 + 4 * lg + q) * OUTD + wcol + nt * 16 + lr] = tot;
    }
}

// o = relu(relu(H) @ out1_W + b1) @ out2_W + b2 ; 8 nodes per block
__global__ __launch_bounds__(128) void head_kernel(
    const float* __restrict__ H,
    const float* __restrict__ W1, const float* __restrict__ b1,
    const float* __restrict__ W2, const float* __restrict__ b2,
    float* __restrict__ o) {
  const int n0 = blockIdx.x * 8;
  const int t = threadIdx.x;
  __shared__ float hr[8][OUTD];
  __shared__ float hid[8][130];
  for (int idx = t; idx < 8 * OUTD; idx += 128) {
    int r = idx >> 8, c = idx & 255;
    float v = H[(n0 + r) * OUTD + c];
    hr[r][c] = v > 0.f ? v : 0.f;
  }
  __syncthreads();
  float acc[8];
  float bb = b1[t];
#pragma unroll
  for (int r = 0; r < 8; ++r) acc[r] = bb;
  for (int k = 0; k < OUTD; ++k) {
    float w = W1[k * HIDD + t];
#pragma unroll
    for (int r = 0; r < 8; ++r) acc[r] += hr[r][k] * w;
  }
#pragma unroll
  for (int r = 0; r < 8; ++r) hid[r][t] = acc[r] > 0.f ? acc[r] : 0.f;
  __syncthreads();
  if (t < 96) {
    int r = t / 12, dd = t - r * 12;
    float a = b2[dd];
    for (int k = 0; k < HIDD; ++k) a += hid[r][k] * W2[k * 12 + dd];
    o[(n0 + r) * 12 + dd] = a;
  }
}

extern "C" void kernel_launch(void* const* d_in, const int* in_sizes, int n_in,
                              void* d_out, int out_size, void* d_ws, size_t ws_size,
                              hipStream_t stream) {
  (void)in_sizes; (void)n_in; (void)out_size; (void)ws_size;
  const float* x    = (const float*)d_in[0];
  const int*   eim  = (const int*)d_in[1];
  const int*   ei0  = (const int*)d_in[2];
  const float* ew0  = (const float*)d_in[3];
  const int*   ei1  = (const int*)d_in[4];
  const float* ew1  = (const float*)d_in[5];
  const int*   ei2  = (const int*)d_in[6];
  const float* ew2  = (const float*)d_in[7];
  const int*   ei3  = (const int*)d_in[8];
  const float* ew3  = (const float*)d_in[9];
  const int*   ei4  = (const int*)d_in[10];
  const float* ew4  = (const float*)d_in[11];
  const float* chebW0 = (const float*)d_in[12];
  const float* chebW1 = (const float*)d_in[13];
  const float* chebb  = (const float*)d_in[14];
  const float* lcW  = (const float*)d_in[15];
  const float* lcb  = (const float*)d_in[16];
  const float* att  = (const float*)d_in[17];
  const float* gzW  = (const float*)d_in[18];
  const float* gzb  = (const float*)d_in[19];
  const float* grW  = (const float*)d_in[20];
  const float* grb  = (const float*)d_in[21];
  const float* ghW  = (const float*)d_in[22];
  const float* ghb  = (const float*)d_in[23];
  const float* lzW  = (const float*)d_in[24];
  const float* lzb  = (const float*)d_in[25];
  const float* lrW  = (const float*)d_in[26];
  const float* lrb  = (const float*)d_in[27];
  const float* lhW  = (const float*)d_in[28];
  const float* lhb  = (const float*)d_in[29];
  const float* o1W  = (const float*)d_in[30];
  const float* o1b  = (const float*)d_in[31];
  const float* o2W  = (const float*)d_in[32];
  const float* o2b  = (const float*)d_in[33];

  float* ws = (float*)d_ws;
  float* out = (float*)d_out;
  float* o_out = out;                 // (N,12) flat
  float* H_out = out + NN * 12;       // (N,256) flat

  (void)hipMemsetAsync(ws, 0, (size_t)WS_ZERO_END * sizeof(float), stream);
  probs_kernel<<<1, 64, 0, stream>>>(att, ws + WS_PROBS);
  deg_kernel<<<(EMAIN + 5 * EREG + 255) / 256, 256, 0, stream>>>(
      eim, ei0, ei1, ei2, ei3, ei4, ew0, ew1, ew2, ew3, ew4,
      ws + WS_DEGM, ws + WS_DEGR);
  dinv_kernel<<<(6 * NN + 255) / 256, 256, 0, stream>>>(
      ws + WS_DEGM, ws + WS_DEGR, ws + WS_DINVM, ws + WS_DINV2M, ws + WS_DINVR);
  norm_kernel<<<(EMAIN + 5 * EREG + 255) / 256, 256, 0, stream>>>(
      eim, ei0, ei1, ei2, ei3, ei4, ew0, ew1, ew2, ew3, ew4,
      ws + WS_DINVM, ws + WS_DINVR, ws + WS_NORMM, ws + WS_NORMR);
  scatter_kernel<<<((EMAIN + 5 * EREG) * 48) / 256, 256, 0, stream>>>(
      x, eim, ei0, ei1, ei2, ei3, ei4,
      ws + WS_NORMM, ws + WS_NORMR, ws + WS_AGGM, ws + WS_TX1);
  prep_parallel_kernel<<<128, 256, 0, stream>>>(
      chebW0, chebW1, chebb, lcW, lcb,
      gzW, gzb, grW, grb, ghW, ghb,
      lzW, lzb, lrW, lrb, lhW, lhb,
      ws);
  prepT_kernel<<<1024, 128, 0, stream>>>(lzW, lrW, lhW, ws);
  gru_mfma_kernel<<<NN / 8, 512, 0, stream>>>(x, ws, H_out);
  head_kernel<<<NN / 8, 128, 0, stream>>>(H_out, o1W, o1b, o2W, o2b, o_out);
}